// Round 4
// baseline (1320.659 us; speedup 1.0000x reference)
//
#include <hip/hip_runtime.h>

#define BN_EPS 1e-5f

// ================= per-node degree (for dinv) =================

__global__ void zero_i32(int* __restrict__ p, int n) {
    int i = blockIdx.x * 256 + threadIdx.x;
    if (i < n) p[i] = 0;
}

__global__ void hist_dst(const int* __restrict__ dst, int* __restrict__ cnt, int E) {
    int e = blockIdx.x * 256 + threadIdx.x;
    if (e < E) atomicAdd(&cnt[dst[e]], 1);
}

__global__ void make_dinv(const int* __restrict__ cnt, float* __restrict__ dinv, int n) {
    int i = blockIdx.x * 256 + threadIdx.x;
    if (i < n) dinv[i] = rsqrtf(1.0f + (float)cnt[i]);
}

// ================= bucket binning (64 dst-nodes per bucket) =================

// bc[b] = sum of cnt_i over the bucket's 64 nodes
__global__ void bucket_sum(const int* __restrict__ cnt, int* __restrict__ bc, int n, int NB) {
    int i = blockIdx.x * 256 + threadIdx.x;
    if (i >= NB) return;
    int base = i * 64;
    int s = 0;
    if (base + 64 <= n) {
        const int4* p = (const int4*)(cnt + base);
#pragma unroll
        for (int k = 0; k < 16; ++k) {
            int4 v = p[k];
            s += v.x + v.y + v.z + v.w;
        }
    } else {
        for (int k = 0; k < 64 && base + k < n; ++k) s += cnt[base + k];
    }
    bc[i] = s;
}

// exclusive scan of bc[0..NB) -> boff (and a cursor copy gcur); NB <= 1024.
__global__ __launch_bounds__(256) void scan_buckets(const int* __restrict__ bc,
                                                    int* __restrict__ boff,
                                                    int* __restrict__ gcur,
                                                    int NB, int E) {
    __shared__ int ls[1024];
    __shared__ int ts[256];
    int t = threadIdx.x;
#pragma unroll
    for (int k = 0; k < 4; ++k) {
        int i = t * 4 + k;
        ls[t * 4 + k] = (i < NB) ? bc[i] : 0;
    }
    __syncthreads();
    int s = ls[t * 4] + ls[t * 4 + 1] + ls[t * 4 + 2] + ls[t * 4 + 3];
    ts[t] = s;
    __syncthreads();
    for (int off = 1; off < 256; off <<= 1) {
        int v = (t >= off) ? ts[t - off] : 0;
        __syncthreads();
        ts[t] += v;
        __syncthreads();
    }
    int ex = ts[t] - s;  // exclusive prefix of this thread's chunk
#pragma unroll
    for (int k = 0; k < 4; ++k) {
        int i = t * 4 + k;
        if (i < NB) {
            boff[i] = ex;
            gcur[i] = ex;
        }
        ex += ls[t * 4 + k];
    }
    if (t == 0) boff[NB] = E;
}

// scatter packed edges (src<<6 | dstLocal) into bucket-grouped tmp.
#define BP_CH 4096
__global__ __launch_bounds__(256) void binpack(const int* __restrict__ src,
                                               const int* __restrict__ dst,
                                               int* __restrict__ gcur,
                                               unsigned* __restrict__ tmp,
                                               int E, int NB) {
    __shared__ int lcnt[1024];
    int t = threadIdx.x;
    int e0 = blockIdx.x * BP_CH;
    for (int i = t; i < NB; i += 256) lcnt[i] = 0;
    __syncthreads();
#pragma unroll
    for (int k = 0; k < BP_CH / 256; ++k) {
        int e = e0 + k * 256 + t;
        if (e < E) atomicAdd(&lcnt[dst[e] >> 6], 1);
    }
    __syncthreads();
    for (int i = t; i < NB; i += 256) {
        int c = lcnt[i];
        if (c > 0) lcnt[i] = atomicAdd(&gcur[i], c);
    }
    __syncthreads();
#pragma unroll
    for (int k = 0; k < BP_CH / 256; ++k) {
        int e = e0 + k * 256 + t;
        if (e < E) {
            int d = dst[e];
            int pos = atomicAdd(&lcnt[d >> 6], 1);
            tmp[pos] = ((unsigned)src[e] << 6) | (unsigned)(d & 63);
        }
    }
}

// ================= GEMM: Hs = BNReLU(X) @ W * dinv[row] =================

#define SXS 68

__global__ __launch_bounds__(256) void gemm64_v2(const float* __restrict__ X,
                                                 const float* __restrict__ W,
                                                 const float* __restrict__ dinv,
                                                 const float* __restrict__ scsh,
                                                 int has_bn, int relu,
                                                 float* __restrict__ Hs, int n) {
    __shared__ float sX[64 * SXS];
    __shared__ float sW[64 * SXS];
    int t = threadIdx.x;
    int c4 = t & 15;
    int base = blockIdx.x * 64;

    {
        const float4* W4 = (const float4*)W;
#pragma unroll
        for (int it = 0; it < 4; ++it) {
            int idx = it * 256 + t;
            int r = idx >> 4;
            float4 v = W4[r * 16 + c4];
            *(float4*)&sW[r * SXS + c4 * 4] = v;
        }
    }
    {
        const float4* X4 = (const float4*)X;
        float4 sc4, sh4;
        if (has_bn) {
            sc4 = ((const float4*)scsh)[c4];
            sh4 = ((const float4*)(scsh + 64))[c4];
        }
#pragma unroll
        for (int it = 0; it < 4; ++it) {
            int idx = it * 256 + t;
            int r = idx >> 4;
            int grow = base + r;
            float4 v = make_float4(0.f, 0.f, 0.f, 0.f);
            if (grow < n) v = X4[(size_t)grow * 16 + c4];
            if (has_bn) {
                v.x = fmaf(v.x, sc4.x, sh4.x);
                v.y = fmaf(v.y, sc4.y, sh4.y);
                v.z = fmaf(v.z, sc4.z, sh4.z);
                v.w = fmaf(v.w, sc4.w, sh4.w);
                if (relu) {
                    v.x = fmaxf(v.x, 0.f); v.y = fmaxf(v.y, 0.f);
                    v.z = fmaxf(v.z, 0.f); v.w = fmaxf(v.w, 0.f);
                }
            }
            *(float4*)&sX[r * SXS + c4 * 4] = v;
        }
    }
    __syncthreads();

    int rgrp = t >> 4;
    float4 acc[4];
#pragma unroll
    for (int ri = 0; ri < 4; ++ri) acc[ri] = make_float4(0.f, 0.f, 0.f, 0.f);

#pragma unroll 4
    for (int k4 = 0; k4 < 16; ++k4) {
        float4 xv[4], wv[4];
#pragma unroll
        for (int ri = 0; ri < 4; ++ri)
            xv[ri] = *(const float4*)&sX[(rgrp + 16 * ri) * SXS + k4 * 4];
#pragma unroll
        for (int kk = 0; kk < 4; ++kk)
            wv[kk] = *(const float4*)&sW[(k4 * 4 + kk) * SXS + c4 * 4];
#pragma unroll
        for (int ri = 0; ri < 4; ++ri) {
            acc[ri].x = fmaf(xv[ri].x, wv[0].x, acc[ri].x);
            acc[ri].y = fmaf(xv[ri].x, wv[0].y, acc[ri].y);
            acc[ri].z = fmaf(xv[ri].x, wv[0].z, acc[ri].z);
            acc[ri].w = fmaf(xv[ri].x, wv[0].w, acc[ri].w);
            acc[ri].x = fmaf(xv[ri].y, wv[1].x, acc[ri].x);
            acc[ri].y = fmaf(xv[ri].y, wv[1].y, acc[ri].y);
            acc[ri].z = fmaf(xv[ri].y, wv[1].z, acc[ri].z);
            acc[ri].w = fmaf(xv[ri].y, wv[1].w, acc[ri].w);
            acc[ri].x = fmaf(xv[ri].z, wv[2].x, acc[ri].x);
            acc[ri].y = fmaf(xv[ri].z, wv[2].y, acc[ri].y);
            acc[ri].z = fmaf(xv[ri].z, wv[2].z, acc[ri].z);
            acc[ri].w = fmaf(xv[ri].z, wv[2].w, acc[ri].w);
            acc[ri].x = fmaf(xv[ri].w, wv[3].x, acc[ri].x);
            acc[ri].y = fmaf(xv[ri].w, wv[3].y, acc[ri].y);
            acc[ri].z = fmaf(xv[ri].w, wv[3].z, acc[ri].z);
            acc[ri].w = fmaf(xv[ri].w, wv[3].w, acc[ri].w);
        }
    }

#pragma unroll
    for (int ri = 0; ri < 4; ++ri) {
        int row = base + rgrp + 16 * ri;
        if (row < n) {
            float dv = dinv[row];
            float4 o = make_float4(acc[ri].x * dv, acc[ri].y * dv,
                                   acc[ri].z * dv, acc[ri].w * dv);
            *(float4*)&Hs[(size_t)row * 64 + c4 * 4] = o;
        }
    }
}

// ================= bucketed aggregate + fused BN stats =================
// One block per bucket of 64 dst nodes. LDS 64x64 accumulator; edges
// gathered coalesced and ds_add_f32'd into the local row. Epilogue adds
// self-loop, scales by dinv, writes Y, and accumulates column sum/sumsq.

__global__ __launch_bounds__(256) void agg_bucket(const float* __restrict__ Hs,
                                                  const unsigned* __restrict__ tmp,
                                                  const int* __restrict__ boff,
                                                  const float* __restrict__ dinv,
                                                  float* __restrict__ Y,
                                                  float* __restrict__ stats, int n) {
    __shared__ float sAcc[64 * 64];
    int b = blockIdx.x;
    int t = threadIdx.x;
    int lane = t & 63;
    int w = t >> 6;
    float4 z4 = make_float4(0.f, 0.f, 0.f, 0.f);
    for (int i = t; i < 1024; i += 256) ((float4*)sAcc)[i] = z4;
    __syncthreads();

    int beg = boff[b], end = boff[b + 1];
    for (int base = beg + w * 64; base < end; base += 256) {
        int m = min(64, end - base);
        unsigned p = (lane < m) ? tmp[base + lane] : 0u;
        int jj = 0;
        for (; jj + 3 < m; jj += 4) {
            unsigned e0 = (unsigned)__shfl((int)p, jj, 64);
            unsigned e1 = (unsigned)__shfl((int)p, jj + 1, 64);
            unsigned e2 = (unsigned)__shfl((int)p, jj + 2, 64);
            unsigned e3 = (unsigned)__shfl((int)p, jj + 3, 64);
            float v0 = Hs[(size_t)(e0 >> 6) * 64 + lane];
            float v1 = Hs[(size_t)(e1 >> 6) * 64 + lane];
            float v2 = Hs[(size_t)(e2 >> 6) * 64 + lane];
            float v3 = Hs[(size_t)(e3 >> 6) * 64 + lane];
            atomicAdd(&sAcc[(e0 & 63u) * 64 + lane], v0);
            atomicAdd(&sAcc[(e1 & 63u) * 64 + lane], v1);
            atomicAdd(&sAcc[(e2 & 63u) * 64 + lane], v2);
            atomicAdd(&sAcc[(e3 & 63u) * 64 + lane], v3);
        }
        for (; jj < m; ++jj) {
            unsigned e0 = (unsigned)__shfl((int)p, jj, 64);
            atomicAdd(&sAcc[(e0 & 63u) * 64 + lane],
                      Hs[(size_t)(e0 >> 6) * 64 + lane]);
        }
    }
    __syncthreads();

    // epilogue: self-loop + dinv scale + write + stats partials
    int c4 = t & 15, rgrp = t >> 4;
    float4 s4 = z4, q4 = z4;
#pragma unroll
    for (int ri = 0; ri < 4; ++ri) {
        int r = rgrp + 16 * ri;
        int node = b * 64 + r;
        if (node < n) {
            float4 a4 = *(float4*)&sAcc[r * 64 + c4 * 4];
            float4 h4 = *(const float4*)&Hs[(size_t)node * 64 + c4 * 4];
            float dv = dinv[node];
            float4 y;
            y.x = (a4.x + h4.x) * dv;
            y.y = (a4.y + h4.y) * dv;
            y.z = (a4.z + h4.z) * dv;
            y.w = (a4.w + h4.w) * dv;
            *(float4*)&Y[(size_t)node * 64 + c4 * 4] = y;
            s4.x += y.x; s4.y += y.y; s4.z += y.z; s4.w += y.w;
            q4.x += y.x * y.x; q4.y += y.y * y.y;
            q4.z += y.z * y.z; q4.w += y.w * y.w;
        }
    }
    __syncthreads();
    *(float4*)&sAcc[rgrp * 64 + c4 * 4] = s4;
    *(float4*)&sAcc[1024 + rgrp * 64 + c4 * 4] = q4;
    __syncthreads();
    if (t < 64) {
        float s = 0.f, q = 0.f;
#pragma unroll
        for (int rg = 0; rg < 16; ++rg) {
            s += sAcc[rg * 64 + t];
            q += sAcc[1024 + rg * 64 + t];
        }
        atomicAdd(&stats[t], s);
        atomicAdd(&stats[64 + t], q);
    }
}

// ================= BN finalize =================

__global__ void bn_finalize(const float* __restrict__ stats,
                            const float* __restrict__ gamma,
                            const float* __restrict__ beta,
                            float* __restrict__ scsh, int n) {
    int j = threadIdx.x;  // 64 threads
    float inv_n = 1.0f / (float)n;
    float mean = stats[j] * inv_n;
    float var = stats[64 + j] * inv_n - mean * mean;
    float sc = gamma[j] * rsqrtf(var + BN_EPS);
    scsh[j] = sc;
    scsh[64 + j] = beta[j] - mean * sc;
}

// ================= global mean pool with fused BN =================

__global__ __launch_bounds__(256) void pool_sum_bn(const float* __restrict__ H,
                                                   const float* __restrict__ scsh,
                                                   const int* __restrict__ batch,
                                                   float* __restrict__ out,
                                                   float* __restrict__ cnt, int n) {
    const int CHUNK = 128;
    int w = blockIdx.x * 4 + (threadIdx.x >> 6);
    int lane = threadIdx.x & 63;
    int start = w * CHUNK;
    if (start >= n) return;
    float sc = scsh[lane], sh = scsh[64 + lane];
    int end = min(start + CHUNK, n);
    int cur = batch[start];
    float acc = 0.f;
    int run = 0;
    for (int i = start; i < end; ++i) {
        int g = batch[i];
        if (g != cur) {
            atomicAdd(&out[(size_t)cur * 64 + lane], acc);
            if (lane == 0) atomicAdd(&cnt[cur], (float)run);
            acc = 0.f;
            run = 0;
            cur = g;
        }
        acc += fmaf(H[(size_t)i * 64 + lane], sc, sh);
        run++;
    }
    atomicAdd(&out[(size_t)cur * 64 + lane], acc);
    if (lane == 0) atomicAdd(&cnt[cur], (float)run);
}

__global__ void pool_div(float* __restrict__ out, const float* __restrict__ cnt, int G) {
    int idx = blockIdx.x * 256 + threadIdx.x;
    if (idx < G * 64) out[idx] /= fmaxf(cnt[idx >> 6], 1.0f);
}

// ================= launch =================

extern "C" void kernel_launch(void* const* d_in, const int* in_sizes, int n_in,
                              void* d_out, int out_size, void* d_ws, size_t ws_size,
                              hipStream_t stream) {
    const float* x     = (const float*)d_in[0];
    const int*   ei    = (const int*)d_in[1];
    const int*   batch = (const int*)d_in[2];
    const float* Wl[3] = {(const float*)d_in[3], (const float*)d_in[7], (const float*)d_in[11]};
    const float* gl[3] = {(const float*)d_in[5], (const float*)d_in[9], (const float*)d_in[13]};
    const float* bl[3] = {(const float*)d_in[6], (const float*)d_in[10], (const float*)d_in[14]};
    float* out = (float*)d_out;

    int E = in_sizes[1] / 2;
    int n = in_sizes[0] / 64;
    int G = out_size / 64;
    const int* src = ei;
    const int* dst = ei + E;
    int NB = (n + 63) / 64;  // buckets of 64 dst nodes (NB <= 1024 for n <= 65536)

    char* ws = (char*)d_ws;
    size_t off = 0;
    auto carve = [&](size_t bytes) {
        void* p = ws + off;
        off += (bytes + 255) & ~(size_t)255;
        return p;
    };
    float*    dinv  = (float*)carve((size_t)n * 4);
    float*    stats = (float*)carve(128 * 4);
    float*    scsh  = (float*)carve(128 * 4);
    float*    cnt_g = (float*)carve((size_t)G * 4);
    float*    bufA  = (float*)carve((size_t)n * 64 * 4);  // Hs
    float*    bufB  = (float*)carve((size_t)n * 64 * 4);  // Y
    int*      cnt_i = (int*)carve((size_t)n * 4);
    int*      bc    = (int*)carve((size_t)NB * 4);
    int*      boff  = (int*)carve(((size_t)NB + 1) * 4);
    int*      gcur  = (int*)carve((size_t)NB * 4);
    unsigned* tmp   = (unsigned*)carve((size_t)E * 4);

    int nb = (n + 255) / 256;

    // ---- degree + binning ----
    zero_i32<<<nb, 256, 0, stream>>>(cnt_i, n);
    hist_dst<<<(E + 255) / 256, 256, 0, stream>>>(dst, cnt_i, E);
    make_dinv<<<nb, 256, 0, stream>>>(cnt_i, dinv, n);
    bucket_sum<<<(NB + 255) / 256, 256, 0, stream>>>(cnt_i, bc, n, NB);
    scan_buckets<<<1, 256, 0, stream>>>(bc, boff, gcur, NB, E);
    binpack<<<(E + BP_CH - 1) / BP_CH, 256, 0, stream>>>(src, dst, gcur, tmp, E, NB);

    int gemm_grid = (n + 63) / 64;

    // ---- 3 GCN layers ----
    const float* cur = x;
    for (int l = 0; l < 3; ++l) {
        gemm64_v2<<<gemm_grid, 256, 0, stream>>>(cur, Wl[l], dinv, scsh,
                                                 l > 0 ? 1 : 0, 1, bufA, n);
        hipMemsetAsync(stats, 0, 128 * sizeof(float), stream);
        agg_bucket<<<NB, 256, 0, stream>>>(bufA, tmp, boff, dinv, bufB, stats, n);
        bn_finalize<<<1, 64, 0, stream>>>(stats, gl[l], bl[l], scsh, n);
        cur = bufB;
    }

    // ---- pool (BN3 fused, no relu) ----
    hipMemsetAsync(out, 0, (size_t)G * 64 * sizeof(float), stream);
    hipMemsetAsync(cnt_g, 0, (size_t)G * sizeof(float), stream);
    int waves = (n + 127) / 128;
    pool_sum_bn<<<(waves + 3) / 4, 256, 0, stream>>>(cur, scsh, batch, out, cnt_g, n);
    pool_div<<<(G * 64 + 255) / 256, 256, 0, stream>>>(out, cnt_g, G);
}

// Round 5
// 367.710 us; speedup vs baseline: 3.5916x; 3.5916x over previous
//
#include <hip/hip_runtime.h>

#define BN_EPS 1e-5f
#define CCH 4096  // edges per partition block

// ================= Phase A: coarse-bucket counting (buckets of 256 dst) =================

__global__ __launch_bounds__(256) void coarse_count(const int* __restrict__ dst,
                                                    int* __restrict__ ccnt, int E) {
    __shared__ int h[256];
    int t = threadIdx.x;
    h[t] = 0;
    __syncthreads();
    int e0 = blockIdx.x * CCH;
#pragma unroll
    for (int k = 0; k < CCH / 256; ++k) {
        int e = e0 + k * 256 + t;
        if (e < E) atomicAdd(&h[dst[e] >> 8], 1);
    }
    __syncthreads();
    if (h[t]) atomicAdd(&ccnt[t], h[t]);
}

// exclusive scan of ccnt[NBC] -> cboff[NBC+1], cursor copy gcur; also rp[n]=E.
__global__ __launch_bounds__(256) void cscan(const int* __restrict__ ccnt,
                                             int* __restrict__ cboff,
                                             int* __restrict__ gcur,
                                             int* __restrict__ rp,
                                             int NBC, int n, int E) {
    __shared__ int s[256];
    int t = threadIdx.x;
    int v = (t < NBC) ? ccnt[t] : 0;
    s[t] = v;
    __syncthreads();
    for (int off = 1; off < 256; off <<= 1) {
        int u = (t >= off) ? s[t - off] : 0;
        __syncthreads();
        s[t] += u;
        __syncthreads();
    }
    int ex = s[t] - v;
    if (t < NBC) { cboff[t] = ex; gcur[t] = ex; }
    if (t == 0) { cboff[NBC] = E; rp[n] = E; }
}

// Phase A scatter: per-block run reservation -> line-granular writes of packed (src<<8|dstLow8)
__global__ __launch_bounds__(256) void cscatter(const int* __restrict__ src,
                                                const int* __restrict__ dst,
                                                int* __restrict__ gcur,
                                                unsigned* __restrict__ tmp, int E) {
    __shared__ int lcnt[256];
    int t = threadIdx.x;
    int e0 = blockIdx.x * CCH;
    lcnt[t] = 0;
    __syncthreads();
#pragma unroll
    for (int k = 0; k < CCH / 256; ++k) {
        int e = e0 + k * 256 + t;
        if (e < E) atomicAdd(&lcnt[dst[e] >> 8], 1);
    }
    __syncthreads();
    int c = lcnt[t];
    __syncthreads();
    if (c > 0) lcnt[t] = atomicAdd(&gcur[t], c);
    __syncthreads();
#pragma unroll
    for (int k = 0; k < CCH / 256; ++k) {
        int e = e0 + k * 256 + t;
        if (e < E) {
            int d = dst[e];
            int pos = atomicAdd(&lcnt[d >> 8], 1);
            tmp[pos] = ((unsigned)src[e] << 8) | (unsigned)(d & 255);
        }
    }
}

// ================= Phase B: per-bucket counting sort -> CSR (rp, u16 col) + dinv =================

#define OUT_CAP 8192

__global__ __launch_bounds__(256) void build_csr(const unsigned* __restrict__ tmp,
                                                 const int* __restrict__ cboff,
                                                 int* __restrict__ rp,
                                                 unsigned short* __restrict__ col,
                                                 float* __restrict__ dinv, int n) {
    __shared__ int hist[256];
    __shared__ int sc[256];
    __shared__ unsigned short outw[OUT_CAP];
    int b = blockIdx.x;
    int t = threadIdx.x;
    int beg = cboff[b], end = cboff[b + 1];
    int m = end - beg;
    hist[t] = 0;
    __syncthreads();
    for (int e = beg + t; e < end; e += 256) atomicAdd(&hist[tmp[e] & 255u], 1);
    __syncthreads();
    int v = hist[t];
    sc[t] = v;
    __syncthreads();
    for (int off = 1; off < 256; off <<= 1) {
        int u = (t >= off) ? sc[t - off] : 0;
        __syncthreads();
        sc[t] += u;
        __syncthreads();
    }
    int excl = sc[t] - v;
    int node = b * 256 + t;
    if (node < n) {
        dinv[node] = rsqrtf(1.0f + (float)v);
        rp[node] = beg + excl;
    }
    hist[t] = excl;  // becomes cursor
    __syncthreads();
    if (m <= OUT_CAP) {
        for (int e = beg + t; e < end; e += 256) {
            unsigned p = tmp[e];
            int pos = atomicAdd(&hist[p & 255u], 1);
            outw[pos] = (unsigned short)(p >> 8);
        }
        __syncthreads();
        for (int i = t; i < m; i += 256) col[beg + i] = outw[i];
    } else {  // degenerate overflow fallback (not expected for this data)
        for (int e = beg + t; e < end; e += 256) {
            unsigned p = tmp[e];
            int pos = atomicAdd(&hist[p & 255u], 1);
            col[beg + pos] = (unsigned short)(p >> 8);
        }
    }
}

// ================= GEMM: Hs = BNReLU(X) @ W * dinv[row] =================

#define SXS 68

__global__ __launch_bounds__(256) void gemm64_v2(const float* __restrict__ X,
                                                 const float* __restrict__ W,
                                                 const float* __restrict__ dinv,
                                                 const float* __restrict__ scsh,
                                                 int has_bn, int relu,
                                                 float* __restrict__ Hs, int n) {
    __shared__ float sX[64 * SXS];
    __shared__ float sW[64 * SXS];
    int t = threadIdx.x;
    int c4 = t & 15;
    int base = blockIdx.x * 64;

    {
        const float4* W4 = (const float4*)W;
#pragma unroll
        for (int it = 0; it < 4; ++it) {
            int idx = it * 256 + t;
            int r = idx >> 4;
            float4 v = W4[r * 16 + c4];
            *(float4*)&sW[r * SXS + c4 * 4] = v;
        }
    }
    {
        const float4* X4 = (const float4*)X;
        float4 sc4, sh4;
        if (has_bn) {
            sc4 = ((const float4*)scsh)[c4];
            sh4 = ((const float4*)(scsh + 64))[c4];
        }
#pragma unroll
        for (int it = 0; it < 4; ++it) {
            int idx = it * 256 + t;
            int r = idx >> 4;
            int grow = base + r;
            float4 v = make_float4(0.f, 0.f, 0.f, 0.f);
            if (grow < n) v = X4[(size_t)grow * 16 + c4];
            if (has_bn) {
                v.x = fmaf(v.x, sc4.x, sh4.x);
                v.y = fmaf(v.y, sc4.y, sh4.y);
                v.z = fmaf(v.z, sc4.z, sh4.z);
                v.w = fmaf(v.w, sc4.w, sh4.w);
                if (relu) {
                    v.x = fmaxf(v.x, 0.f); v.y = fmaxf(v.y, 0.f);
                    v.z = fmaxf(v.z, 0.f); v.w = fmaxf(v.w, 0.f);
                }
            }
            *(float4*)&sX[r * SXS + c4 * 4] = v;
        }
    }
    __syncthreads();

    int rgrp = t >> 4;
    float4 acc[4];
#pragma unroll
    for (int ri = 0; ri < 4; ++ri) acc[ri] = make_float4(0.f, 0.f, 0.f, 0.f);

#pragma unroll 4
    for (int k4 = 0; k4 < 16; ++k4) {
        float4 xv[4], wv[4];
#pragma unroll
        for (int ri = 0; ri < 4; ++ri)
            xv[ri] = *(const float4*)&sX[(rgrp + 16 * ri) * SXS + k4 * 4];
#pragma unroll
        for (int kk = 0; kk < 4; ++kk)
            wv[kk] = *(const float4*)&sW[(k4 * 4 + kk) * SXS + c4 * 4];
#pragma unroll
        for (int ri = 0; ri < 4; ++ri) {
            acc[ri].x = fmaf(xv[ri].x, wv[0].x, acc[ri].x);
            acc[ri].y = fmaf(xv[ri].x, wv[0].y, acc[ri].y);
            acc[ri].z = fmaf(xv[ri].x, wv[0].z, acc[ri].z);
            acc[ri].w = fmaf(xv[ri].x, wv[0].w, acc[ri].w);
            acc[ri].x = fmaf(xv[ri].y, wv[1].x, acc[ri].x);
            acc[ri].y = fmaf(xv[ri].y, wv[1].y, acc[ri].y);
            acc[ri].z = fmaf(xv[ri].y, wv[1].z, acc[ri].z);
            acc[ri].w = fmaf(xv[ri].y, wv[1].w, acc[ri].w);
            acc[ri].x = fmaf(xv[ri].z, wv[2].x, acc[ri].x);
            acc[ri].y = fmaf(xv[ri].z, wv[2].y, acc[ri].y);
            acc[ri].z = fmaf(xv[ri].z, wv[2].z, acc[ri].z);
            acc[ri].w = fmaf(xv[ri].z, wv[2].w, acc[ri].w);
            acc[ri].x = fmaf(xv[ri].w, wv[3].x, acc[ri].x);
            acc[ri].y = fmaf(xv[ri].w, wv[3].y, acc[ri].y);
            acc[ri].z = fmaf(xv[ri].w, wv[3].z, acc[ri].z);
            acc[ri].w = fmaf(xv[ri].w, wv[3].w, acc[ri].w);
        }
    }

#pragma unroll
    for (int ri = 0; ri < 4; ++ri) {
        int row = base + rgrp + 16 * ri;
        if (row < n) {
            float dv = dinv[row];
            float4 o = make_float4(acc[ri].x * dv, acc[ri].y * dv,
                                   acc[ri].z * dv, acc[ri].w * dv);
            *(float4*)&Hs[(size_t)row * 64 + c4 * 4] = o;
        }
    }
}

// ================= CSR gather-aggregate, quarter-wave float4 =================
// wave per node; each 16-lane quarter gathers one edge's full row as float4;
// cross-quarter butterfly folds partials.

__global__ __launch_bounds__(256) void agg(const float* __restrict__ Hs,
                                           const int* __restrict__ rp,
                                           const unsigned short* __restrict__ col,
                                           const float* __restrict__ dinv,
                                           float* __restrict__ Y, int n) {
    int d = blockIdx.x * 4 + (threadIdx.x >> 6);
    int lane = threadIdx.x & 63;
    if (d >= n) return;
    int q = lane >> 4;   // quarter 0..3
    int c = lane & 15;   // float4 column group
    float ax = 0.f, ay = 0.f, az = 0.f, aw = 0.f;
    int beg = rp[d], end = rp[d + 1];
    for (int b = beg; b < end; b += 64) {
        int m = min(64, end - b);
        int myidx = (lane < m) ? (int)col[b + lane] : 0;
        int jj = 0;
        for (; jj + 7 < m; jj += 8) {
            int s0 = __shfl(myidx, jj + q, 64);
            int s1 = __shfl(myidx, jj + 4 + q, 64);
            float4 v0 = *(const float4*)&Hs[(size_t)s0 * 64 + c * 4];
            float4 v1 = *(const float4*)&Hs[(size_t)s1 * 64 + c * 4];
            ax += v0.x + v1.x; ay += v0.y + v1.y;
            az += v0.z + v1.z; aw += v0.w + v1.w;
        }
        for (; jj < m; jj += 4) {
            int e = jj + q;
            int es = min(e, m - 1);
            int s0 = __shfl(myidx, es, 64);  // all lanes execute the shfl
            if (e < m) {
                float4 v = *(const float4*)&Hs[(size_t)s0 * 64 + c * 4];
                ax += v.x; ay += v.y; az += v.z; aw += v.w;
            }
        }
    }
    // fold quarters: lanes q^1(16) and q^2(32)
    ax += __shfl_xor(ax, 16, 64); ay += __shfl_xor(ay, 16, 64);
    az += __shfl_xor(az, 16, 64); aw += __shfl_xor(aw, 16, 64);
    ax += __shfl_xor(ax, 32, 64); ay += __shfl_xor(ay, 32, 64);
    az += __shfl_xor(az, 32, 64); aw += __shfl_xor(aw, 32, 64);
    if (q == 0) {
        float dv = dinv[d];
        float4 h = *(const float4*)&Hs[(size_t)d * 64 + c * 4];
        float4 y;
        y.x = (ax + h.x) * dv; y.y = (ay + h.y) * dv;
        y.z = (az + h.z) * dv; y.w = (aw + h.w) * dv;
        *(float4*)&Y[(size_t)d * 64 + c * 4] = y;
    }
}

// ================= BN stats + finalize =================

__global__ __launch_bounds__(256) void bn_stats(const float* __restrict__ Y,
                                                float* __restrict__ stats, int n) {
    int t = threadIdx.x;
    int j = t & 63;
    int rg = t >> 6;
    float s = 0.f, s2 = 0.f;
    for (int i = blockIdx.x * 4 + rg; i < n; i += gridDim.x * 4) {
        float v = Y[(size_t)i * 64 + j];
        s += v;
        s2 += v * v;
    }
    __shared__ float red[256], red2[256];
    red[t] = s;
    red2[t] = s2;
    __syncthreads();
    if (rg == 0) {
        s  = red[j]  + red[64 + j]  + red[128 + j]  + red[192 + j];
        s2 = red2[j] + red2[64 + j] + red2[128 + j] + red2[192 + j];
        atomicAdd(&stats[j], s);
        atomicAdd(&stats[64 + j], s2);
    }
}

__global__ void bn_finalize(const float* __restrict__ stats,
                            const float* __restrict__ gamma,
                            const float* __restrict__ beta,
                            float* __restrict__ scsh, int n) {
    int j = threadIdx.x;  // 64 threads
    float inv_n = 1.0f / (float)n;
    float mean = stats[j] * inv_n;
    float var = stats[64 + j] * inv_n - mean * mean;
    float sc = gamma[j] * rsqrtf(var + BN_EPS);
    scsh[j] = sc;
    scsh[64 + j] = beta[j] - mean * sc;
}

// ================= global mean pool with fused BN =================

__global__ __launch_bounds__(256) void pool_sum_bn(const float* __restrict__ H,
                                                   const float* __restrict__ scsh,
                                                   const int* __restrict__ batch,
                                                   float* __restrict__ out,
                                                   float* __restrict__ cnt, int n) {
    const int CHUNK = 128;
    int w = blockIdx.x * 4 + (threadIdx.x >> 6);
    int lane = threadIdx.x & 63;
    int start = w * CHUNK;
    if (start >= n) return;
    float sc = scsh[lane], sh = scsh[64 + lane];
    int end = min(start + CHUNK, n);
    int cur = batch[start];
    float acc = 0.f;
    int run = 0;
    for (int i = start; i < end; ++i) {
        int g = batch[i];
        if (g != cur) {
            atomicAdd(&out[(size_t)cur * 64 + lane], acc);
            if (lane == 0) atomicAdd(&cnt[cur], (float)run);
            acc = 0.f;
            run = 0;
            cur = g;
        }
        acc += fmaf(H[(size_t)i * 64 + lane], sc, sh);
        run++;
    }
    atomicAdd(&out[(size_t)cur * 64 + lane], acc);
    if (lane == 0) atomicAdd(&cnt[cur], (float)run);
}

__global__ void pool_div(float* __restrict__ out, const float* __restrict__ cnt, int G) {
    int idx = blockIdx.x * 256 + threadIdx.x;
    if (idx < G * 64) out[idx] /= fmaxf(cnt[idx >> 6], 1.0f);
}

// ================= launch =================

extern "C" void kernel_launch(void* const* d_in, const int* in_sizes, int n_in,
                              void* d_out, int out_size, void* d_ws, size_t ws_size,
                              hipStream_t stream) {
    const float* x     = (const float*)d_in[0];
    const int*   ei    = (const int*)d_in[1];
    const int*   batch = (const int*)d_in[2];
    const float* Wl[3] = {(const float*)d_in[3], (const float*)d_in[7], (const float*)d_in[11]};
    const float* gl[3] = {(const float*)d_in[5], (const float*)d_in[9], (const float*)d_in[13]};
    const float* bl[3] = {(const float*)d_in[6], (const float*)d_in[10], (const float*)d_in[14]};
    float* out = (float*)d_out;

    int E = in_sizes[1] / 2;
    int n = in_sizes[0] / 64;
    int G = out_size / 64;
    const int* src = ei;
    const int* dst = ei + E;
    int NBC = (n + 255) / 256;  // coarse buckets (<=256 for n<=65536)

    char* ws = (char*)d_ws;
    size_t off = 0;
    auto carve = [&](size_t bytes) {
        void* p = ws + off;
        off += (bytes + 255) & ~(size_t)255;
        return p;
    };
    float*          dinv  = (float*)carve((size_t)n * 4);
    float*          stats = (float*)carve(128 * 4);
    float*          scsh  = (float*)carve(128 * 4);
    float*          cnt_g = (float*)carve((size_t)G * 4);
    float*          bufA  = (float*)carve((size_t)n * 64 * 4);  // Hs
    float*          bufB  = (float*)carve((size_t)n * 64 * 4);  // Y
    int*            ccnt  = (int*)carve(256 * 4);
    int*            cboff = (int*)carve(257 * 4);
    int*            gcur  = (int*)carve(256 * 4);
    int*            rp    = (int*)carve(((size_t)n + 1) * 4);
    unsigned*       tmp   = (unsigned*)carve((size_t)E * 4);
    unsigned short* col   = (unsigned short*)carve((size_t)E * 2);

    int pgrid = (E + CCH - 1) / CCH;

    // ---- CSR build (radix partition) + dinv ----
    hipMemsetAsync(ccnt, 0, 256 * sizeof(int), stream);
    coarse_count<<<pgrid, 256, 0, stream>>>(dst, ccnt, E);
    cscan<<<1, 256, 0, stream>>>(ccnt, cboff, gcur, rp, NBC, n, E);
    cscatter<<<pgrid, 256, 0, stream>>>(src, dst, gcur, tmp, E);
    build_csr<<<NBC, 256, 0, stream>>>(tmp, cboff, rp, col, dinv, n);

    int gemm_grid = (n + 63) / 64;
    int agg_grid = (n + 3) / 4;

    // ---- 3 GCN layers ----
    const float* cur = x;
    for (int l = 0; l < 3; ++l) {
        gemm64_v2<<<gemm_grid, 256, 0, stream>>>(cur, Wl[l], dinv, scsh,
                                                 l > 0 ? 1 : 0, 1, bufA, n);
        hipMemsetAsync(stats, 0, 128 * sizeof(float), stream);
        agg<<<agg_grid, 256, 0, stream>>>(bufA, rp, col, dinv, bufB, n);
        bn_stats<<<256, 256, 0, stream>>>(bufB, stats, n);
        bn_finalize<<<1, 64, 0, stream>>>(stats, gl[l], bl[l], scsh, n);
        cur = bufB;
    }

    // ---- pool (BN3 fused, no relu) ----
    hipMemsetAsync(out, 0, (size_t)G * 64 * sizeof(float), stream);
    hipMemsetAsync(cnt_g, 0, (size_t)G * sizeof(float), stream);
    int waves = (n + 127) / 128;
    pool_sum_bn<<<(waves + 3) / 4, 256, 0, stream>>>(cur, scsh, batch, out, cnt_g, n);
    pool_div<<<(G * 64 + 255) / 256, 256, 0, stream>>>(out, cnt_g, G);
}

// Round 6
// 339.374 us; speedup vs baseline: 3.8915x; 1.0835x over previous
//
#include <hip/hip_runtime.h>

#define BN_EPS 1e-5f
#define CCH 4096  // edges per partition block

// ================= Phase A: coarse-bucket counting (buckets of 256 dst) =================

__global__ __launch_bounds__(256) void coarse_count(const int* __restrict__ dst,
                                                    int* __restrict__ ccnt, int E) {
    __shared__ int h[256];
    int t = threadIdx.x;
    h[t] = 0;
    __syncthreads();
    int e0 = blockIdx.x * CCH;
#pragma unroll
    for (int k = 0; k < CCH / 256; ++k) {
        int e = e0 + k * 256 + t;
        if (e < E) atomicAdd(&h[dst[e] >> 8], 1);
    }
    __syncthreads();
    if (h[t]) atomicAdd(&ccnt[t], h[t]);
}

// exclusive scan of ccnt[NBC] -> cboff[NBC+1], cursor copy gcur; also rp[n]=E.
__global__ __launch_bounds__(256) void cscan(const int* __restrict__ ccnt,
                                             int* __restrict__ cboff,
                                             int* __restrict__ gcur,
                                             int* __restrict__ rp,
                                             int NBC, int n, int E) {
    __shared__ int s[256];
    int t = threadIdx.x;
    int v = (t < NBC) ? ccnt[t] : 0;
    s[t] = v;
    __syncthreads();
    for (int off = 1; off < 256; off <<= 1) {
        int u = (t >= off) ? s[t - off] : 0;
        __syncthreads();
        s[t] += u;
        __syncthreads();
    }
    int ex = s[t] - v;
    if (t < NBC) { cboff[t] = ex; gcur[t] = ex; }
    if (t == 0) { cboff[NBC] = E; rp[n] = E; }
}

// Phase A scatter: per-block run reservation -> line-granular writes of packed (src<<8|dstLow8)
__global__ __launch_bounds__(256) void cscatter(const int* __restrict__ src,
                                                const int* __restrict__ dst,
                                                int* __restrict__ gcur,
                                                unsigned* __restrict__ tmp, int E) {
    __shared__ int lcnt[256];
    int t = threadIdx.x;
    int e0 = blockIdx.x * CCH;
    lcnt[t] = 0;
    __syncthreads();
#pragma unroll
    for (int k = 0; k < CCH / 256; ++k) {
        int e = e0 + k * 256 + t;
        if (e < E) atomicAdd(&lcnt[dst[e] >> 8], 1);
    }
    __syncthreads();
    int c = lcnt[t];
    __syncthreads();
    if (c > 0) lcnt[t] = atomicAdd(&gcur[t], c);
    __syncthreads();
#pragma unroll
    for (int k = 0; k < CCH / 256; ++k) {
        int e = e0 + k * 256 + t;
        if (e < E) {
            int d = dst[e];
            int pos = atomicAdd(&lcnt[d >> 8], 1);
            tmp[pos] = ((unsigned)src[e] << 8) | (unsigned)(d & 255);
        }
    }
}

// ================= Phase B: per-bucket counting sort -> CSR (rp, u16 col) + dinv =================

#define OUT_CAP 8192

__global__ __launch_bounds__(256) void build_csr(const unsigned* __restrict__ tmp,
                                                 const int* __restrict__ cboff,
                                                 int* __restrict__ rp,
                                                 unsigned short* __restrict__ col,
                                                 float* __restrict__ dinv, int n) {
    __shared__ int hist[256];
    __shared__ int sc[256];
    __shared__ unsigned short outw[OUT_CAP];
    int b = blockIdx.x;
    int t = threadIdx.x;
    int beg = cboff[b], end = cboff[b + 1];
    int m = end - beg;
    hist[t] = 0;
    __syncthreads();
    for (int e = beg + t; e < end; e += 256) atomicAdd(&hist[tmp[e] & 255u], 1);
    __syncthreads();
    int v = hist[t];
    sc[t] = v;
    __syncthreads();
    for (int off = 1; off < 256; off <<= 1) {
        int u = (t >= off) ? sc[t - off] : 0;
        __syncthreads();
        sc[t] += u;
        __syncthreads();
    }
    int excl = sc[t] - v;
    int node = b * 256 + t;
    if (node < n) {
        dinv[node] = rsqrtf(1.0f + (float)v);
        rp[node] = beg + excl;
    }
    hist[t] = excl;  // becomes cursor
    __syncthreads();
    if (m <= OUT_CAP) {
        for (int e = beg + t; e < end; e += 256) {
            unsigned p = tmp[e];
            int pos = atomicAdd(&hist[p & 255u], 1);
            outw[pos] = (unsigned short)(p >> 8);
        }
        __syncthreads();
        for (int i = t; i < m; i += 256) col[beg + i] = outw[i];
    } else {  // degenerate overflow fallback (not expected for this data)
        for (int e = beg + t; e < end; e += 256) {
            unsigned p = tmp[e];
            int pos = atomicAdd(&hist[p & 255u], 1);
            col[beg + pos] = (unsigned short)(p >> 8);
        }
    }
}

// ================= GEMM: Hs = BNReLU(X) @ W * dinv[row] =================

#define SXS 68

__global__ __launch_bounds__(256) void gemm64_v2(const float* __restrict__ X,
                                                 const float* __restrict__ W,
                                                 const float* __restrict__ dinv,
                                                 const float* __restrict__ scsh,
                                                 int has_bn, int relu,
                                                 float* __restrict__ Hs, int n) {
    __shared__ float sX[64 * SXS];
    __shared__ float sW[64 * SXS];
    int t = threadIdx.x;
    int c4 = t & 15;
    int base = blockIdx.x * 64;

    {
        const float4* W4 = (const float4*)W;
#pragma unroll
        for (int it = 0; it < 4; ++it) {
            int idx = it * 256 + t;
            int r = idx >> 4;
            float4 v = W4[r * 16 + c4];
            *(float4*)&sW[r * SXS + c4 * 4] = v;
        }
    }
    {
        const float4* X4 = (const float4*)X;
        float4 sc4, sh4;
        if (has_bn) {
            sc4 = ((const float4*)scsh)[c4];
            sh4 = ((const float4*)(scsh + 64))[c4];
        }
#pragma unroll
        for (int it = 0; it < 4; ++it) {
            int idx = it * 256 + t;
            int r = idx >> 4;
            int grow = base + r;
            float4 v = make_float4(0.f, 0.f, 0.f, 0.f);
            if (grow < n) v = X4[(size_t)grow * 16 + c4];
            if (has_bn) {
                v.x = fmaf(v.x, sc4.x, sh4.x);
                v.y = fmaf(v.y, sc4.y, sh4.y);
                v.z = fmaf(v.z, sc4.z, sh4.z);
                v.w = fmaf(v.w, sc4.w, sh4.w);
                if (relu) {
                    v.x = fmaxf(v.x, 0.f); v.y = fmaxf(v.y, 0.f);
                    v.z = fmaxf(v.z, 0.f); v.w = fmaxf(v.w, 0.f);
                }
            }
            *(float4*)&sX[r * SXS + c4 * 4] = v;
        }
    }
    __syncthreads();

    int rgrp = t >> 4;
    float4 acc[4];
#pragma unroll
    for (int ri = 0; ri < 4; ++ri) acc[ri] = make_float4(0.f, 0.f, 0.f, 0.f);

#pragma unroll 4
    for (int k4 = 0; k4 < 16; ++k4) {
        float4 xv[4], wv[4];
#pragma unroll
        for (int ri = 0; ri < 4; ++ri)
            xv[ri] = *(const float4*)&sX[(rgrp + 16 * ri) * SXS + k4 * 4];
#pragma unroll
        for (int kk = 0; kk < 4; ++kk)
            wv[kk] = *(const float4*)&sW[(k4 * 4 + kk) * SXS + c4 * 4];
#pragma unroll
        for (int ri = 0; ri < 4; ++ri) {
            acc[ri].x = fmaf(xv[ri].x, wv[0].x, acc[ri].x);
            acc[ri].y = fmaf(xv[ri].x, wv[0].y, acc[ri].y);
            acc[ri].z = fmaf(xv[ri].x, wv[0].z, acc[ri].z);
            acc[ri].w = fmaf(xv[ri].x, wv[0].w, acc[ri].w);
            acc[ri].x = fmaf(xv[ri].y, wv[1].x, acc[ri].x);
            acc[ri].y = fmaf(xv[ri].y, wv[1].y, acc[ri].y);
            acc[ri].z = fmaf(xv[ri].y, wv[1].z, acc[ri].z);
            acc[ri].w = fmaf(xv[ri].y, wv[1].w, acc[ri].w);
            acc[ri].x = fmaf(xv[ri].z, wv[2].x, acc[ri].x);
            acc[ri].y = fmaf(xv[ri].z, wv[2].y, acc[ri].y);
            acc[ri].z = fmaf(xv[ri].z, wv[2].z, acc[ri].z);
            acc[ri].w = fmaf(xv[ri].z, wv[2].w, acc[ri].w);
            acc[ri].x = fmaf(xv[ri].w, wv[3].x, acc[ri].x);
            acc[ri].y = fmaf(xv[ri].w, wv[3].y, acc[ri].y);
            acc[ri].z = fmaf(xv[ri].w, wv[3].z, acc[ri].z);
            acc[ri].w = fmaf(xv[ri].w, wv[3].w, acc[ri].w);
        }
    }

#pragma unroll
    for (int ri = 0; ri < 4; ++ri) {
        int row = base + rgrp + 16 * ri;
        if (row < n) {
            float dv = dinv[row];
            float4 o = make_float4(acc[ri].x * dv, acc[ri].y * dv,
                                   acc[ri].z * dv, acc[ri].w * dv);
            *(float4*)&Hs[(size_t)row * 64 + c4 * 4] = o;
        }
    }
}

// ================= CSR gather-aggregate, quarter-wave float4 =================

__global__ __launch_bounds__(256) void agg(const float* __restrict__ Hs,
                                           const int* __restrict__ rp,
                                           const unsigned short* __restrict__ col,
                                           const float* __restrict__ dinv,
                                           float* __restrict__ Y, int n) {
    int d = blockIdx.x * 4 + (threadIdx.x >> 6);
    int lane = threadIdx.x & 63;
    if (d >= n) return;
    int q = lane >> 4;   // quarter 0..3
    int c = lane & 15;   // float4 column group
    float ax = 0.f, ay = 0.f, az = 0.f, aw = 0.f;
    int beg = rp[d], end = rp[d + 1];
    for (int b = beg; b < end; b += 64) {
        int m = min(64, end - b);
        int myidx = (lane < m) ? (int)col[b + lane] : 0;
        int jj = 0;
        for (; jj + 7 < m; jj += 8) {
            int s0 = __shfl(myidx, jj + q, 64);
            int s1 = __shfl(myidx, jj + 4 + q, 64);
            float4 v0 = *(const float4*)&Hs[(size_t)s0 * 64 + c * 4];
            float4 v1 = *(const float4*)&Hs[(size_t)s1 * 64 + c * 4];
            ax += v0.x + v1.x; ay += v0.y + v1.y;
            az += v0.z + v1.z; aw += v0.w + v1.w;
        }
        for (; jj < m; jj += 4) {
            int e = jj + q;
            int es = min(e, m - 1);
            int s0 = __shfl(myidx, es, 64);  // all lanes execute the shfl
            if (e < m) {
                float4 v = *(const float4*)&Hs[(size_t)s0 * 64 + c * 4];
                ax += v.x; ay += v.y; az += v.z; aw += v.w;
            }
        }
    }
    ax += __shfl_xor(ax, 16, 64); ay += __shfl_xor(ay, 16, 64);
    az += __shfl_xor(az, 16, 64); aw += __shfl_xor(aw, 16, 64);
    ax += __shfl_xor(ax, 32, 64); ay += __shfl_xor(ay, 32, 64);
    az += __shfl_xor(az, 32, 64); aw += __shfl_xor(aw, 32, 64);
    if (q == 0) {
        float dv = dinv[d];
        float4 h = *(const float4*)&Hs[(size_t)d * 64 + c * 4];
        float4 y;
        y.x = (ax + h.x) * dv; y.y = (ay + h.y) * dv;
        y.z = (az + h.z) * dv; y.w = (aw + h.w) * dv;
        *(float4*)&Y[(size_t)d * 64 + c * 4] = y;
    }
}

// ================= BN stats + finalize =================

__global__ __launch_bounds__(256) void bn_stats(const float* __restrict__ Y,
                                                float* __restrict__ stats, int n) {
    int t = threadIdx.x;
    int j = t & 63;
    int rg = t >> 6;
    float s = 0.f, s2 = 0.f;
    for (int i = blockIdx.x * 4 + rg; i < n; i += gridDim.x * 4) {
        float v = Y[(size_t)i * 64 + j];
        s += v;
        s2 += v * v;
    }
    __shared__ float red[256], red2[256];
    red[t] = s;
    red2[t] = s2;
    __syncthreads();
    if (rg == 0) {
        s  = red[j]  + red[64 + j]  + red[128 + j]  + red[192 + j];
        s2 = red2[j] + red2[64 + j] + red2[128 + j] + red2[192 + j];
        atomicAdd(&stats[j], s);
        atomicAdd(&stats[64 + j], s2);
    }
}

__global__ void bn_finalize(const float* __restrict__ stats,
                            const float* __restrict__ gamma,
                            const float* __restrict__ beta,
                            float* __restrict__ scsh, int n) {
    int j = threadIdx.x;  // 64 threads
    float inv_n = 1.0f / (float)n;
    float mean = stats[j] * inv_n;
    float var = stats[64 + j] * inv_n - mean * mean;
    float sc = gamma[j] * rsqrtf(var + BN_EPS);
    scsh[j] = sc;
    scsh[64 + j] = beta[j] - mean * sc;
}

// ================= global mean pool with fused BN =================
// CHUNK=16: 3125 waves (782 blocks) -- R4's CHUNK=128 gave only 98 blocks
// (3.3% occupancy, latency-starved at 48 us).

__global__ __launch_bounds__(256) void pool_sum_bn(const float* __restrict__ H,
                                                   const float* __restrict__ scsh,
                                                   const int* __restrict__ batch,
                                                   float* __restrict__ out,
                                                   float* __restrict__ cnt, int n) {
    const int CHUNK = 16;
    int w = blockIdx.x * 4 + (threadIdx.x >> 6);
    int lane = threadIdx.x & 63;
    int start = w * CHUNK;
    if (start >= n) return;
    float sc = scsh[lane], sh = scsh[64 + lane];
    int end = min(start + CHUNK, n);
    int cur = batch[start];
    float acc = 0.f;
    int run = 0;
    for (int i = start; i < end; ++i) {
        int g = batch[i];
        if (g != cur) {
            atomicAdd(&out[(size_t)cur * 64 + lane], acc);
            if (lane == 0) atomicAdd(&cnt[cur], (float)run);
            acc = 0.f;
            run = 0;
            cur = g;
        }
        acc += fmaf(H[(size_t)i * 64 + lane], sc, sh);
        run++;
    }
    atomicAdd(&out[(size_t)cur * 64 + lane], acc);
    if (lane == 0) atomicAdd(&cnt[cur], (float)run);
}

__global__ void pool_div(float* __restrict__ out, const float* __restrict__ cnt, int G) {
    int idx = blockIdx.x * 256 + threadIdx.x;
    if (idx < G * 64) out[idx] /= fmaxf(cnt[idx >> 6], 1.0f);
}

// ================= launch =================

extern "C" void kernel_launch(void* const* d_in, const int* in_sizes, int n_in,
                              void* d_out, int out_size, void* d_ws, size_t ws_size,
                              hipStream_t stream) {
    const float* x     = (const float*)d_in[0];
    const int*   ei    = (const int*)d_in[1];
    const int*   batch = (const int*)d_in[2];
    const float* Wl[3] = {(const float*)d_in[3], (const float*)d_in[7], (const float*)d_in[11]};
    const float* gl[3] = {(const float*)d_in[5], (const float*)d_in[9], (const float*)d_in[13]};
    const float* bl[3] = {(const float*)d_in[6], (const float*)d_in[10], (const float*)d_in[14]};
    float* out = (float*)d_out;

    int E = in_sizes[1] / 2;
    int n = in_sizes[0] / 64;
    int G = out_size / 64;
    const int* src = ei;
    const int* dst = ei + E;
    int NBC = (n + 255) / 256;  // coarse buckets (<=256 for n<=65536)

    char* ws = (char*)d_ws;
    size_t off = 0;
    auto carve = [&](size_t bytes) {
        void* p = ws + off;
        off += (bytes + 255) & ~(size_t)255;
        return p;
    };
    float*          dinv  = (float*)carve((size_t)n * 4);
    float*          stats = (float*)carve(128 * 4);
    float*          scsh  = (float*)carve(128 * 4);
    float*          cnt_g = (float*)carve((size_t)G * 4);
    float*          bufA  = (float*)carve((size_t)n * 64 * 4);  // Hs
    float*          bufB  = (float*)carve((size_t)n * 64 * 4);  // Y
    int*            ccnt  = (int*)carve(256 * 4);
    int*            cboff = (int*)carve(257 * 4);
    int*            gcur  = (int*)carve(256 * 4);
    int*            rp    = (int*)carve(((size_t)n + 1) * 4);
    unsigned*       tmp   = (unsigned*)carve((size_t)E * 4);
    unsigned short* col   = (unsigned short*)carve((size_t)E * 2);

    int pgrid = (E + CCH - 1) / CCH;

    // ---- CSR build (radix partition) + dinv ----
    hipMemsetAsync(ccnt, 0, 256 * sizeof(int), stream);
    coarse_count<<<pgrid, 256, 0, stream>>>(dst, ccnt, E);
    cscan<<<1, 256, 0, stream>>>(ccnt, cboff, gcur, rp, NBC, n, E);
    cscatter<<<pgrid, 256, 0, stream>>>(src, dst, gcur, tmp, E);
    build_csr<<<NBC, 256, 0, stream>>>(tmp, cboff, rp, col, dinv, n);

    int gemm_grid = (n + 63) / 64;
    int agg_grid = (n + 3) / 4;

    // ---- 3 GCN layers ----
    const float* cur = x;
    for (int l = 0; l < 3; ++l) {
        gemm64_v2<<<gemm_grid, 256, 0, stream>>>(cur, Wl[l], dinv, scsh,
                                                 l > 0 ? 1 : 0, 1, bufA, n);
        hipMemsetAsync(stats, 0, 128 * sizeof(float), stream);
        agg<<<agg_grid, 256, 0, stream>>>(bufA, rp, col, dinv, bufB, n);
        bn_stats<<<256, 256, 0, stream>>>(bufB, stats, n);
        bn_finalize<<<1, 64, 0, stream>>>(stats, gl[l], bl[l], scsh, n);
        cur = bufB;
    }

    // ---- pool (BN3 fused, no relu) ----
    hipMemsetAsync(out, 0, (size_t)G * 64 * sizeof(float), stream);
    hipMemsetAsync(cnt_g, 0, (size_t)G * sizeof(float), stream);
    int waves = (n + 15) / 16;
    pool_sum_bn<<<(waves + 3) / 4, 256, 0, stream>>>(cur, scsh, batch, out, cnt_g, n);
    pool_div<<<(G * 64 + 255) / 256, 256, 0, stream>>>(out, cnt_g, G);
}

// Round 7
// 262.814 us; speedup vs baseline: 5.0251x; 1.2913x over previous
//
#include <hip/hip_runtime.h>

#define BN_EPS 1e-5f
#define CCH 4096   // edges per partition block
#define NSLICE 32  // stats partial slices (contention limiter)

// ---------------- bf16 helpers ----------------

__device__ inline unsigned pack_bf16x2(float x, float y) {
    unsigned ux = __float_as_uint(x);
    ux = (ux + 0x7FFFu + ((ux >> 16) & 1u)) >> 16;
    unsigned uy = __float_as_uint(y);
    uy = (uy + 0x7FFFu + ((uy >> 16) & 1u)) >> 16;
    return ux | (uy << 16);
}

__device__ inline void bf16x2_add(unsigned u, float& a, float& b) {
    a += __uint_as_float((u & 0xFFFFu) << 16);
    b += __uint_as_float(u & 0xFFFF0000u);
}

// ================= Phase A: coarse-bucket counting (buckets of 256 dst) =================

__global__ __launch_bounds__(256) void coarse_count(const int* __restrict__ dst,
                                                    int* __restrict__ ccnt, int E) {
    __shared__ int h[256];
    int t = threadIdx.x;
    h[t] = 0;
    __syncthreads();
    int e0 = blockIdx.x * CCH;
#pragma unroll
    for (int k = 0; k < CCH / 256; ++k) {
        int e = e0 + k * 256 + t;
        if (e < E) atomicAdd(&h[dst[e] >> 8], 1);
    }
    __syncthreads();
    if (h[t]) atomicAdd(&ccnt[t], h[t]);
}

// exclusive scan of ccnt -> cboff/gcur; rp[n]=E; zero cnt_g.
__global__ __launch_bounds__(256) void cscan(const int* __restrict__ ccnt,
                                             int* __restrict__ cboff,
                                             int* __restrict__ gcur,
                                             int* __restrict__ rp,
                                             float* __restrict__ cnt_g,
                                             int NBC, int n, int E, int G) {
    __shared__ int s[256];
    int t = threadIdx.x;
    int v = (t < NBC) ? ccnt[t] : 0;
    s[t] = v;
    __syncthreads();
    for (int off = 1; off < 256; off <<= 1) {
        int u = (t >= off) ? s[t - off] : 0;
        __syncthreads();
        s[t] += u;
        __syncthreads();
    }
    int ex = s[t] - v;
    if (t < NBC) { cboff[t] = ex; gcur[t] = ex; }
    if (t == 0) { cboff[NBC] = E; rp[n] = E; }
    for (int i = t; i < G; i += 256) cnt_g[i] = 0.f;
}

// Phase A scatter: per-block run reservation -> line-granular writes of packed (src<<8|dstLow8)
__global__ __launch_bounds__(256) void cscatter(const int* __restrict__ src,
                                                const int* __restrict__ dst,
                                                int* __restrict__ gcur,
                                                unsigned* __restrict__ tmp, int E) {
    __shared__ int lcnt[256];
    int t = threadIdx.x;
    int e0 = blockIdx.x * CCH;
    lcnt[t] = 0;
    __syncthreads();
#pragma unroll
    for (int k = 0; k < CCH / 256; ++k) {
        int e = e0 + k * 256 + t;
        if (e < E) atomicAdd(&lcnt[dst[e] >> 8], 1);
    }
    __syncthreads();
    int c = lcnt[t];
    __syncthreads();
    if (c > 0) lcnt[t] = atomicAdd(&gcur[t], c);
    __syncthreads();
#pragma unroll
    for (int k = 0; k < CCH / 256; ++k) {
        int e = e0 + k * 256 + t;
        if (e < E) {
            int d = dst[e];
            int pos = atomicAdd(&lcnt[d >> 8], 1);
            tmp[pos] = ((unsigned)src[e] << 8) | (unsigned)(d & 255);
        }
    }
}

// ================= Phase B: per-bucket counting sort -> CSR (rp, u16 col) + dinv =================

#define OUT_CAP 8192

__global__ __launch_bounds__(256) void build_csr(const unsigned* __restrict__ tmp,
                                                 const int* __restrict__ cboff,
                                                 int* __restrict__ rp,
                                                 unsigned short* __restrict__ col,
                                                 float* __restrict__ dinv, int n) {
    __shared__ int hist[256];
    __shared__ int sc[256];
    __shared__ unsigned short outw[OUT_CAP];
    int b = blockIdx.x;
    int t = threadIdx.x;
    int beg = cboff[b], end = cboff[b + 1];
    int m = end - beg;
    hist[t] = 0;
    __syncthreads();
    for (int e = beg + t; e < end; e += 256) atomicAdd(&hist[tmp[e] & 255u], 1);
    __syncthreads();
    int v = hist[t];
    sc[t] = v;
    __syncthreads();
    for (int off = 1; off < 256; off <<= 1) {
        int u = (t >= off) ? sc[t - off] : 0;
        __syncthreads();
        sc[t] += u;
        __syncthreads();
    }
    int excl = sc[t] - v;
    int node = b * 256 + t;
    if (node < n) {
        dinv[node] = rsqrtf(1.0f + (float)v);
        rp[node] = beg + excl;
    }
    hist[t] = excl;  // becomes cursor
    __syncthreads();
    if (m <= OUT_CAP) {
        for (int e = beg + t; e < end; e += 256) {
            unsigned p = tmp[e];
            int pos = atomicAdd(&hist[p & 255u], 1);
            outw[pos] = (unsigned short)(p >> 8);
        }
        __syncthreads();
        for (int i = t; i < m; i += 256) col[beg + i] = outw[i];
    } else {  // overflow fallback
        for (int e = beg + t; e < end; e += 256) {
            unsigned p = tmp[e];
            int pos = atomicAdd(&hist[p & 255u], 1);
            col[beg + pos] = (unsigned short)(p >> 8);
        }
    }
}

// ================= graph-size histogram (once per call) =================

__global__ __launch_bounds__(256) void cnt_hist(const int* __restrict__ batch,
                                                float* __restrict__ cnt, int n, int G) {
    __shared__ int h[512];
    int t = threadIdx.x;
    if (G <= 512) {
        for (int i = t; i < 512; i += 256) h[i] = 0;
        __syncthreads();
        for (int i = blockIdx.x * 256 + t; i < n; i += gridDim.x * 256)
            atomicAdd(&h[batch[i]], 1);
        __syncthreads();
        for (int i = t; i < G; i += 256)
            if (h[i]) atomicAdd(&cnt[i], (float)h[i]);
    } else {
        for (int i = blockIdx.x * 256 + t; i < n; i += gridDim.x * 256)
            atomicAdd(&cnt[batch[i]], 1.0f);
    }
}

// ================= GEMM: Hs(bf16) = BNReLU(X) @ W * dinv[row] =================

#define SXS 68

__global__ __launch_bounds__(256) void gemm64_v2(const float* __restrict__ X,
                                                 const float* __restrict__ W,
                                                 const float* __restrict__ dinv,
                                                 const float* __restrict__ scsh,
                                                 int has_bn, int relu,
                                                 unsigned* __restrict__ Hs, int n) {
    __shared__ float sX[64 * SXS];
    __shared__ float sW[64 * SXS];
    int t = threadIdx.x;
    int c4 = t & 15;
    int base = blockIdx.x * 64;

    {
        const float4* W4 = (const float4*)W;
#pragma unroll
        for (int it = 0; it < 4; ++it) {
            int idx = it * 256 + t;
            int r = idx >> 4;
            float4 v = W4[r * 16 + c4];
            *(float4*)&sW[r * SXS + c4 * 4] = v;
        }
    }
    {
        const float4* X4 = (const float4*)X;
        float4 sc4, sh4;
        if (has_bn) {
            sc4 = ((const float4*)scsh)[c4];
            sh4 = ((const float4*)(scsh + 64))[c4];
        }
#pragma unroll
        for (int it = 0; it < 4; ++it) {
            int idx = it * 256 + t;
            int r = idx >> 4;
            int grow = base + r;
            float4 v = make_float4(0.f, 0.f, 0.f, 0.f);
            if (grow < n) v = X4[(size_t)grow * 16 + c4];
            if (has_bn) {
                v.x = fmaf(v.x, sc4.x, sh4.x);
                v.y = fmaf(v.y, sc4.y, sh4.y);
                v.z = fmaf(v.z, sc4.z, sh4.z);
                v.w = fmaf(v.w, sc4.w, sh4.w);
                if (relu) {
                    v.x = fmaxf(v.x, 0.f); v.y = fmaxf(v.y, 0.f);
                    v.z = fmaxf(v.z, 0.f); v.w = fmaxf(v.w, 0.f);
                }
            }
            *(float4*)&sX[r * SXS + c4 * 4] = v;
        }
    }
    __syncthreads();

    int rgrp = t >> 4;
    float4 acc[4];
#pragma unroll
    for (int ri = 0; ri < 4; ++ri) acc[ri] = make_float4(0.f, 0.f, 0.f, 0.f);

#pragma unroll 4
    for (int k4 = 0; k4 < 16; ++k4) {
        float4 xv[4], wv[4];
#pragma unroll
        for (int ri = 0; ri < 4; ++ri)
            xv[ri] = *(const float4*)&sX[(rgrp + 16 * ri) * SXS + k4 * 4];
#pragma unroll
        for (int kk = 0; kk < 4; ++kk)
            wv[kk] = *(const float4*)&sW[(k4 * 4 + kk) * SXS + c4 * 4];
#pragma unroll
        for (int ri = 0; ri < 4; ++ri) {
            acc[ri].x = fmaf(xv[ri].x, wv[0].x, acc[ri].x);
            acc[ri].y = fmaf(xv[ri].x, wv[0].y, acc[ri].y);
            acc[ri].z = fmaf(xv[ri].x, wv[0].z, acc[ri].z);
            acc[ri].w = fmaf(xv[ri].x, wv[0].w, acc[ri].w);
            acc[ri].x = fmaf(xv[ri].y, wv[1].x, acc[ri].x);
            acc[ri].y = fmaf(xv[ri].y, wv[1].y, acc[ri].y);
            acc[ri].z = fmaf(xv[ri].y, wv[1].z, acc[ri].z);
            acc[ri].w = fmaf(xv[ri].y, wv[1].w, acc[ri].w);
            acc[ri].x = fmaf(xv[ri].z, wv[2].x, acc[ri].x);
            acc[ri].y = fmaf(xv[ri].z, wv[2].y, acc[ri].y);
            acc[ri].z = fmaf(xv[ri].z, wv[2].z, acc[ri].z);
            acc[ri].w = fmaf(xv[ri].z, wv[2].w, acc[ri].w);
            acc[ri].x = fmaf(xv[ri].w, wv[3].x, acc[ri].x);
            acc[ri].y = fmaf(xv[ri].w, wv[3].y, acc[ri].y);
            acc[ri].z = fmaf(xv[ri].w, wv[3].z, acc[ri].z);
            acc[ri].w = fmaf(xv[ri].w, wv[3].w, acc[ri].w);
        }
    }

#pragma unroll
    for (int ri = 0; ri < 4; ++ri) {
        int row = base + rgrp + 16 * ri;
        if (row < n) {
            float dv = dinv[row];
            uint2 o2;
            o2.x = pack_bf16x2(acc[ri].x * dv, acc[ri].y * dv);
            o2.y = pack_bf16x2(acc[ri].z * dv, acc[ri].w * dv);
            ((uint2*)Hs)[(size_t)row * 16 + c4] = o2;
        }
    }
}

// ================= CSR gather-aggregate (bf16 Hs) + fused BN-stat partials =================

__global__ __launch_bounds__(256) void agg(const uint2* __restrict__ Hs2,
                                           const int* __restrict__ rp,
                                           const unsigned short* __restrict__ col,
                                           const float* __restrict__ dinv,
                                           float* __restrict__ Y,
                                           float* __restrict__ part, int n) {
    __shared__ float sS[4][64];
    __shared__ float sQ[4][64];
    int t = threadIdx.x;
    int w = t >> 6;
    int lane = t & 63;
    int q = lane >> 4;
    int c = lane & 15;
    int d = blockIdx.x * 4 + w;
    bool valid = d < n;
    int dc = valid ? d : 0;
    float ax = 0.f, ay = 0.f, az = 0.f, aw = 0.f;
    int beg = valid ? rp[dc] : 0;
    int end = valid ? rp[dc + 1] : 0;
    for (int b = beg; b < end; b += 64) {
        int m = min(64, end - b);
        int myidx = (lane < m) ? (int)col[b + lane] : 0;
        int jj = 0;
        for (; jj + 7 < m; jj += 8) {
            int s0 = __shfl(myidx, jj + q, 64);
            int s1 = __shfl(myidx, jj + 4 + q, 64);
            uint2 v0 = Hs2[(size_t)s0 * 16 + c];
            uint2 v1 = Hs2[(size_t)s1 * 16 + c];
            bf16x2_add(v0.x, ax, ay); bf16x2_add(v0.y, az, aw);
            bf16x2_add(v1.x, ax, ay); bf16x2_add(v1.y, az, aw);
        }
        for (; jj < m; jj += 4) {
            int e = jj + q;
            int s0 = __shfl(myidx, min(e, m - 1), 64);
            if (e < m) {
                uint2 v = Hs2[(size_t)s0 * 16 + c];
                bf16x2_add(v.x, ax, ay); bf16x2_add(v.y, az, aw);
            }
        }
    }
    ax += __shfl_xor(ax, 16, 64); ay += __shfl_xor(ay, 16, 64);
    az += __shfl_xor(az, 16, 64); aw += __shfl_xor(aw, 16, 64);
    ax += __shfl_xor(ax, 32, 64); ay += __shfl_xor(ay, 32, 64);
    az += __shfl_xor(az, 32, 64); aw += __shfl_xor(aw, 32, 64);
    if (q == 0) {
        float4 y = make_float4(0.f, 0.f, 0.f, 0.f);
        if (valid) {
            float hx = 0.f, hy = 0.f, hz = 0.f, hw = 0.f;
            uint2 hv = Hs2[(size_t)dc * 16 + c];
            bf16x2_add(hv.x, hx, hy); bf16x2_add(hv.y, hz, hw);
            float dv = dinv[dc];
            y.x = (ax + hx) * dv; y.y = (ay + hy) * dv;
            y.z = (az + hz) * dv; y.w = (aw + hw) * dv;
            *(float4*)&Y[(size_t)dc * 64 + c * 4] = y;
        }
        *(float4*)&sS[w][c * 4] = y;
        float4 yq = make_float4(y.x * y.x, y.y * y.y, y.z * y.z, y.w * y.w);
        *(float4*)&sQ[w][c * 4] = yq;
    }
    __syncthreads();
    if (t < 64) {
        float s = sS[0][t] + sS[1][t] + sS[2][t] + sS[3][t];
        float qq = sQ[0][t] + sQ[1][t] + sQ[2][t] + sQ[3][t];
        float* dst = part + (size_t)(blockIdx.x & (NSLICE - 1)) * 128;
        atomicAdd(&dst[t], s);
        atomicAdd(&dst[64 + t], qq);
    }
}

// layer-3 variant: no Y materialization; per-graph raw-y sums via atomics.
__global__ __launch_bounds__(256) void agg_pool(const uint2* __restrict__ Hs2,
                                                const int* __restrict__ rp,
                                                const unsigned short* __restrict__ col,
                                                const float* __restrict__ dinv,
                                                const int* __restrict__ batch,
                                                float* __restrict__ out,
                                                float* __restrict__ part, int n) {
    __shared__ float sS[4][64];
    __shared__ float sQ[4][64];
    __shared__ int sG[4];
    int t = threadIdx.x;
    int w = t >> 6;
    int lane = t & 63;
    int q = lane >> 4;
    int c = lane & 15;
    int d = blockIdx.x * 4 + w;
    bool valid = d < n;
    int dc = valid ? d : 0;
    float ax = 0.f, ay = 0.f, az = 0.f, aw = 0.f;
    int beg = valid ? rp[dc] : 0;
    int end = valid ? rp[dc + 1] : 0;
    for (int b = beg; b < end; b += 64) {
        int m = min(64, end - b);
        int myidx = (lane < m) ? (int)col[b + lane] : 0;
        int jj = 0;
        for (; jj + 7 < m; jj += 8) {
            int s0 = __shfl(myidx, jj + q, 64);
            int s1 = __shfl(myidx, jj + 4 + q, 64);
            uint2 v0 = Hs2[(size_t)s0 * 16 + c];
            uint2 v1 = Hs2[(size_t)s1 * 16 + c];
            bf16x2_add(v0.x, ax, ay); bf16x2_add(v0.y, az, aw);
            bf16x2_add(v1.x, ax, ay); bf16x2_add(v1.y, az, aw);
        }
        for (; jj < m; jj += 4) {
            int e = jj + q;
            int s0 = __shfl(myidx, min(e, m - 1), 64);
            if (e < m) {
                uint2 v = Hs2[(size_t)s0 * 16 + c];
                bf16x2_add(v.x, ax, ay); bf16x2_add(v.y, az, aw);
            }
        }
    }
    ax += __shfl_xor(ax, 16, 64); ay += __shfl_xor(ay, 16, 64);
    az += __shfl_xor(az, 16, 64); aw += __shfl_xor(aw, 16, 64);
    ax += __shfl_xor(ax, 32, 64); ay += __shfl_xor(ay, 32, 64);
    az += __shfl_xor(az, 32, 64); aw += __shfl_xor(aw, 32, 64);
    if (q == 0) {
        float4 y = make_float4(0.f, 0.f, 0.f, 0.f);
        if (valid) {
            float hx = 0.f, hy = 0.f, hz = 0.f, hw = 0.f;
            uint2 hv = Hs2[(size_t)dc * 16 + c];
            bf16x2_add(hv.x, hx, hy); bf16x2_add(hv.y, hz, hw);
            float dv = dinv[dc];
            y.x = (ax + hx) * dv; y.y = (ay + hy) * dv;
            y.z = (az + hz) * dv; y.w = (aw + hw) * dv;
        }
        *(float4*)&sS[w][c * 4] = y;
        float4 yq = make_float4(y.x * y.x, y.y * y.y, y.z * y.z, y.w * y.w);
        *(float4*)&sQ[w][c * 4] = yq;
        if (lane == 0) sG[w] = valid ? batch[dc] : -1;
    }
    __syncthreads();
    if (t < 64) {
        float s = sS[0][t] + sS[1][t] + sS[2][t] + sS[3][t];
        float qq = sQ[0][t] + sQ[1][t] + sQ[2][t] + sQ[3][t];
        float* dst = part + (size_t)(blockIdx.x & (NSLICE - 1)) * 128;
        atomicAdd(&dst[t], s);
        atomicAdd(&dst[64 + t], qq);
        int g0 = sG[0], g1 = sG[1], g2 = sG[2], g3 = sG[3];
        if (g0 >= 0 && g0 == g1 && g0 == g2 && g0 == g3) {
            atomicAdd(&out[(size_t)g0 * 64 + t], s);
        } else {
            if (g0 >= 0) atomicAdd(&out[(size_t)g0 * 64 + t], sS[0][t]);
            if (g1 >= 0) atomicAdd(&out[(size_t)g1 * 64 + t], sS[1][t]);
            if (g2 >= 0) atomicAdd(&out[(size_t)g2 * 64 + t], sS[2][t]);
            if (g3 >= 0) atomicAdd(&out[(size_t)g3 * 64 + t], sS[3][t]);
        }
    }
}

// ================= stats reduce + BN coefficient finalize =================

__global__ void reduce_finalize(const float* __restrict__ part,
                                const float* __restrict__ gamma,
                                const float* __restrict__ beta,
                                float* __restrict__ scsh, float inv_n) {
    __shared__ float red[128];
    int t = threadIdx.x;  // 128 threads
    float s = 0.f;
    for (int k = 0; k < NSLICE; ++k) s += part[k * 128 + t];
    red[t] = s;
    __syncthreads();
    if (t < 64) {
        float mean = red[t] * inv_n;
        float var = red[64 + t] * inv_n - mean * mean;
        float sc = gamma[t] * rsqrtf(var + BN_EPS);
        scsh[t] = sc;
        scsh[64 + t] = beta[t] - mean * sc;
    }
}

// ================= final: out = BN3-affine(graph mean) =================

__global__ void pool_div(float* __restrict__ out, const float* __restrict__ cnt,
                         const float* __restrict__ scsh, int G) {
    int idx = blockIdx.x * 256 + threadIdx.x;
    if (idx >= G * 64) return;
    int j = idx & 63, g = idx >> 6;
    float c = cnt[g];
    float sc = scsh[j], sh = scsh[64 + j];
    out[idx] = (c > 0.5f) ? fmaf(sc, out[idx] / c, sh) : 0.f;
}

// ================= launch =================

extern "C" void kernel_launch(void* const* d_in, const int* in_sizes, int n_in,
                              void* d_out, int out_size, void* d_ws, size_t ws_size,
                              hipStream_t stream) {
    const float* x     = (const float*)d_in[0];
    const int*   ei    = (const int*)d_in[1];
    const int*   batch = (const int*)d_in[2];
    const float* Wl[3] = {(const float*)d_in[3], (const float*)d_in[7], (const float*)d_in[11]};
    const float* gl[3] = {(const float*)d_in[5], (const float*)d_in[9], (const float*)d_in[13]};
    const float* bl[3] = {(const float*)d_in[6], (const float*)d_in[10], (const float*)d_in[14]};
    float* out = (float*)d_out;

    int E = in_sizes[1] / 2;
    int n = in_sizes[0] / 64;
    int G = out_size / 64;
    const int* src = ei;
    const int* dst = ei + E;
    int NBC = (n + 255) / 256;  // coarse buckets (<=256 for n<=65536)
    float inv_n = 1.0f / (float)n;

    char* ws = (char*)d_ws;
    size_t off = 0;
    auto carve = [&](size_t bytes) {
        void* p = ws + off;
        off += (bytes + 255) & ~(size_t)255;
        return p;
    };
    float*          dinv  = (float*)carve((size_t)n * 4);
    float*          part  = (float*)carve(3 * NSLICE * 128 * 4);
    float*          scsh  = (float*)carve(128 * 4);
    float*          cnt_g = (float*)carve((size_t)G * 4);
    unsigned*       Hs    = (unsigned*)carve((size_t)n * 32 * 4);  // n*64 bf16
    float*          Ybuf  = (float*)carve((size_t)n * 64 * 4);
    int*            ccnt  = (int*)carve(256 * 4);
    int*            cboff = (int*)carve(257 * 4);
    int*            gcur  = (int*)carve(256 * 4);
    int*            rp    = (int*)carve(((size_t)n + 1) * 4);
    unsigned*       tmp   = (unsigned*)carve((size_t)E * 4);
    unsigned short* col   = (unsigned short*)carve((size_t)E * 2);

    int pgrid = (E + CCH - 1) / CCH;

    // ---- setup: CSR build + dinv + graph counts + zeroed accumulators ----
    hipMemsetAsync(out, 0, (size_t)G * 64 * sizeof(float), stream);
    hipMemsetAsync(ccnt, 0, 256 * sizeof(int), stream);
    hipMemsetAsync(part, 0, 3 * NSLICE * 128 * sizeof(float), stream);
    coarse_count<<<pgrid, 256, 0, stream>>>(dst, ccnt, E);
    cscan<<<1, 256, 0, stream>>>(ccnt, cboff, gcur, rp, cnt_g, NBC, n, E, G);
    cscatter<<<pgrid, 256, 0, stream>>>(src, dst, gcur, tmp, E);
    build_csr<<<NBC, 256, 0, stream>>>(tmp, cboff, rp, col, dinv, n);
    cnt_hist<<<64, 256, 0, stream>>>(batch, cnt_g, n, G);

    int gemm_grid = (n + 63) / 64;
    int agg_grid = (n + 3) / 4;

    // ---- 3 GCN layers ----
    const float* cur = x;
    for (int l = 0; l < 3; ++l) {
        float* part_l = part + (size_t)l * NSLICE * 128;
        gemm64_v2<<<gemm_grid, 256, 0, stream>>>(cur, Wl[l], dinv, scsh,
                                                 l > 0 ? 1 : 0, 1, Hs, n);
        if (l < 2) {
            agg<<<agg_grid, 256, 0, stream>>>((const uint2*)Hs, rp, col, dinv,
                                              Ybuf, part_l, n);
        } else {
            agg_pool<<<agg_grid, 256, 0, stream>>>((const uint2*)Hs, rp, col, dinv,
                                                   batch, out, part_l, n);
        }
        reduce_finalize<<<1, 128, 0, stream>>>(part_l, gl[l], bl[l], scsh, inv_n);
        cur = Ybuf;
    }

    // ---- final BN3-affine on graph means ----
    pool_div<<<(G * 64 + 255) / 256, 256, 0, stream>>>(out, cnt_g, scsh, G);
}

// Round 8
// 256.419 us; speedup vs baseline: 5.1504x; 1.0249x over previous
//
#include <hip/hip_runtime.h>

#define BN_EPS 1e-5f
#define CCH 4096   // edges per partition block
#define NSLICE 32  // stats partial slices (contention limiter)

// ---------------- bf16 helpers ----------------

__device__ inline unsigned pack_bf16x2(float x, float y) {
    unsigned ux = __float_as_uint(x);
    ux = (ux + 0x7FFFu + ((ux >> 16) & 1u)) >> 16;
    unsigned uy = __float_as_uint(y);
    uy = (uy + 0x7FFFu + ((uy >> 16) & 1u)) >> 16;
    return ux | (uy << 16);
}

__device__ inline void bf16x2_add(unsigned u, float& a, float& b) {
    a += __uint_as_float((u & 0xFFFFu) << 16);
    b += __uint_as_float(u & 0xFFFF0000u);
}

// ================= Phase A: coarse-bucket counting (buckets of 256 dst) =================

__global__ __launch_bounds__(256) void coarse_count(const int* __restrict__ dst,
                                                    int* __restrict__ ccnt, int E) {
    __shared__ int h[256];
    int t = threadIdx.x;
    h[t] = 0;
    __syncthreads();
    int e0 = blockIdx.x * CCH;
#pragma unroll
    for (int k = 0; k < CCH / 256; ++k) {
        int e = e0 + k * 256 + t;
        if (e < E) atomicAdd(&h[dst[e] >> 8], 1);
    }
    __syncthreads();
    if (h[t]) atomicAdd(&ccnt[t], h[t]);
}

// exclusive scan of ccnt -> cboff/gcur; rp[n]=E; zero cnt_g and out.
__global__ __launch_bounds__(256) void cscan(const int* __restrict__ ccnt,
                                             int* __restrict__ cboff,
                                             int* __restrict__ gcur,
                                             int* __restrict__ rp,
                                             float* __restrict__ cnt_g,
                                             float* __restrict__ out,
                                             int NBC, int n, int E, int G) {
    __shared__ int s[256];
    int t = threadIdx.x;
    int v = (t < NBC) ? ccnt[t] : 0;
    s[t] = v;
    __syncthreads();
    for (int off = 1; off < 256; off <<= 1) {
        int u = (t >= off) ? s[t - off] : 0;
        __syncthreads();
        s[t] += u;
        __syncthreads();
    }
    int ex = s[t] - v;
    if (t < NBC) { cboff[t] = ex; gcur[t] = ex; }
    if (t == 0) { cboff[NBC] = E; rp[n] = E; }
    for (int i = t; i < G; i += 256) cnt_g[i] = 0.f;
    int tot = G * 64;
    for (int i = t; i < tot; i += 256) out[i] = 0.f;
}

// Phase A scatter: per-block run reservation -> line-granular writes of packed (src<<8|dstLow8)
__global__ __launch_bounds__(256) void cscatter(const int* __restrict__ src,
                                                const int* __restrict__ dst,
                                                int* __restrict__ gcur,
                                                unsigned* __restrict__ tmp, int E) {
    __shared__ int lcnt[256];
    int t = threadIdx.x;
    int e0 = blockIdx.x * CCH;
    lcnt[t] = 0;
    __syncthreads();
#pragma unroll
    for (int k = 0; k < CCH / 256; ++k) {
        int e = e0 + k * 256 + t;
        if (e < E) atomicAdd(&lcnt[dst[e] >> 8], 1);
    }
    __syncthreads();
    int c = lcnt[t];
    __syncthreads();
    if (c > 0) lcnt[t] = atomicAdd(&gcur[t], c);
    __syncthreads();
#pragma unroll
    for (int k = 0; k < CCH / 256; ++k) {
        int e = e0 + k * 256 + t;
        if (e < E) {
            int d = dst[e];
            int pos = atomicAdd(&lcnt[d >> 8], 1);
            tmp[pos] = ((unsigned)src[e] << 8) | (unsigned)(d & 255);
        }
    }
}

// ================= Phase B: per-bucket counting sort -> CSR (rp, u16 col) + dinv
//                   + fused graph-size histogram (tail) =================

#define OUT_CAP 8192

__global__ __launch_bounds__(256) void build_csr(const unsigned* __restrict__ tmp,
                                                 const int* __restrict__ cboff,
                                                 int* __restrict__ rp,
                                                 unsigned short* __restrict__ col,
                                                 float* __restrict__ dinv,
                                                 const int* __restrict__ batch,
                                                 float* __restrict__ cnt_g,
                                                 int n, int G) {
    __shared__ int hist[256];
    __shared__ int sc[256];
    __shared__ unsigned short outw[OUT_CAP];
    __shared__ int h[512];
    int b = blockIdx.x;
    int t = threadIdx.x;
    int beg = cboff[b], end = cboff[b + 1];
    int m = end - beg;
    hist[t] = 0;
    __syncthreads();
    for (int e = beg + t; e < end; e += 256) atomicAdd(&hist[tmp[e] & 255u], 1);
    __syncthreads();
    int v = hist[t];
    sc[t] = v;
    __syncthreads();
    for (int off = 1; off < 256; off <<= 1) {
        int u = (t >= off) ? sc[t - off] : 0;
        __syncthreads();
        sc[t] += u;
        __syncthreads();
    }
    int excl = sc[t] - v;
    int node = b * 256 + t;
    if (node < n) {
        dinv[node] = rsqrtf(1.0f + (float)v);
        rp[node] = beg + excl;
    }
    hist[t] = excl;  // becomes cursor
    __syncthreads();
    if (m <= OUT_CAP) {
        for (int e = beg + t; e < end; e += 256) {
            unsigned p = tmp[e];
            int pos = atomicAdd(&hist[p & 255u], 1);
            outw[pos] = (unsigned short)(p >> 8);
        }
        __syncthreads();
        for (int i = t; i < m; i += 256) col[beg + i] = outw[i];
    } else {  // overflow fallback
        for (int e = beg + t; e < end; e += 256) {
            unsigned p = tmp[e];
            int pos = atomicAdd(&hist[p & 255u], 1);
            col[beg + pos] = (unsigned short)(p >> 8);
        }
    }
    // ---- fused graph-size histogram ----
    if (G <= 512) {
        __syncthreads();
        for (int i = t; i < 512; i += 256) h[i] = 0;
        __syncthreads();
        for (int i = b * 256 + t; i < n; i += gridDim.x * 256)
            atomicAdd(&h[batch[i]], 1);
        __syncthreads();
        for (int i = t; i < G; i += 256)
            if (h[i]) atomicAdd(&cnt_g[i], (float)h[i]);
    } else {
        for (int i = b * 256 + t; i < n; i += gridDim.x * 256)
            atomicAdd(&cnt_g[batch[i]], 1.0f);
    }
}

// ================= GEMM: Hs(bf16) = BNReLU(X) @ W * dinv[row] =================
// BN coefficients computed in-block from the previous layer's stat partials
// (16 KB L2-broadcast read per block -- replaces the reduce_finalize kernel).

#define SXS 68

__global__ __launch_bounds__(256) void gemm64_v2(const float* __restrict__ X,
                                                 const float* __restrict__ W,
                                                 const float* __restrict__ dinv,
                                                 const float* __restrict__ part,
                                                 const float* __restrict__ gamma,
                                                 const float* __restrict__ beta,
                                                 int has_bn, float inv_n,
                                                 unsigned* __restrict__ Hs, int n) {
    __shared__ float sX[64 * SXS];
    __shared__ float sW[64 * SXS];
    __shared__ float s_scsh[128];
    int t = threadIdx.x;
    int c4 = t & 15;
    int base = blockIdx.x * 64;

    if (has_bn) {
        if (t < 128) {
            float s = 0.f;
#pragma unroll
            for (int k = 0; k < NSLICE; ++k) s += part[k * 128 + t];
            s_scsh[t] = s;
        }
        __syncthreads();
        if (t < 64) {
            float mean = s_scsh[t] * inv_n;
            float var = s_scsh[64 + t] * inv_n - mean * mean;
            float sc = gamma[t] * rsqrtf(var + BN_EPS);
            s_scsh[t] = sc;
            s_scsh[64 + t] = beta[t] - mean * sc;
        }
        __syncthreads();
    }

    {
        const float4* W4 = (const float4*)W;
#pragma unroll
        for (int it = 0; it < 4; ++it) {
            int idx = it * 256 + t;
            int r = idx >> 4;
            float4 v = W4[r * 16 + c4];
            *(float4*)&sW[r * SXS + c4 * 4] = v;
        }
    }
    {
        const float4* X4 = (const float4*)X;
        float4 sc4, sh4;
        if (has_bn) {
            sc4 = *(const float4*)&s_scsh[c4 * 4];
            sh4 = *(const float4*)&s_scsh[64 + c4 * 4];
        }
#pragma unroll
        for (int it = 0; it < 4; ++it) {
            int idx = it * 256 + t;
            int r = idx >> 4;
            int grow = base + r;
            float4 v = make_float4(0.f, 0.f, 0.f, 0.f);
            if (grow < n) v = X4[(size_t)grow * 16 + c4];
            if (has_bn) {
                v.x = fmaxf(fmaf(v.x, sc4.x, sh4.x), 0.f);
                v.y = fmaxf(fmaf(v.y, sc4.y, sh4.y), 0.f);
                v.z = fmaxf(fmaf(v.z, sc4.z, sh4.z), 0.f);
                v.w = fmaxf(fmaf(v.w, sc4.w, sh4.w), 0.f);
            }
            *(float4*)&sX[r * SXS + c4 * 4] = v;
        }
    }
    __syncthreads();

    int rgrp = t >> 4;
    float4 acc[4];
#pragma unroll
    for (int ri = 0; ri < 4; ++ri) acc[ri] = make_float4(0.f, 0.f, 0.f, 0.f);

#pragma unroll 4
    for (int k4 = 0; k4 < 16; ++k4) {
        float4 xv[4], wv[4];
#pragma unroll
        for (int ri = 0; ri < 4; ++ri)
            xv[ri] = *(const float4*)&sX[(rgrp + 16 * ri) * SXS + k4 * 4];
#pragma unroll
        for (int kk = 0; kk < 4; ++kk)
            wv[kk] = *(const float4*)&sW[(k4 * 4 + kk) * SXS + c4 * 4];
#pragma unroll
        for (int ri = 0; ri < 4; ++ri) {
            acc[ri].x = fmaf(xv[ri].x, wv[0].x, acc[ri].x);
            acc[ri].y = fmaf(xv[ri].x, wv[0].y, acc[ri].y);
            acc[ri].z = fmaf(xv[ri].x, wv[0].z, acc[ri].z);
            acc[ri].w = fmaf(xv[ri].x, wv[0].w, acc[ri].w);
            acc[ri].x = fmaf(xv[ri].y, wv[1].x, acc[ri].x);
            acc[ri].y = fmaf(xv[ri].y, wv[1].y, acc[ri].y);
            acc[ri].z = fmaf(xv[ri].y, wv[1].z, acc[ri].z);
            acc[ri].w = fmaf(xv[ri].y, wv[1].w, acc[ri].w);
            acc[ri].x = fmaf(xv[ri].z, wv[2].x, acc[ri].x);
            acc[ri].y = fmaf(xv[ri].z, wv[2].y, acc[ri].y);
            acc[ri].z = fmaf(xv[ri].z, wv[2].z, acc[ri].z);
            acc[ri].w = fmaf(xv[ri].z, wv[2].w, acc[ri].w);
            acc[ri].x = fmaf(xv[ri].w, wv[3].x, acc[ri].x);
            acc[ri].y = fmaf(xv[ri].w, wv[3].y, acc[ri].y);
            acc[ri].z = fmaf(xv[ri].w, wv[3].z, acc[ri].z);
            acc[ri].w = fmaf(xv[ri].w, wv[3].w, acc[ri].w);
        }
    }

#pragma unroll
    for (int ri = 0; ri < 4; ++ri) {
        int row = base + rgrp + 16 * ri;
        if (row < n) {
            float dv = dinv[row];
            uint2 o2;
            o2.x = pack_bf16x2(acc[ri].x * dv, acc[ri].y * dv);
            o2.y = pack_bf16x2(acc[ri].z * dv, acc[ri].w * dv);
            ((uint2*)Hs)[(size_t)row * 16 + c4] = o2;
        }
    }
}

// ================= CSR gather-aggregate (bf16 Hs) + fused BN-stat partials =================

__global__ __launch_bounds__(256) void agg(const uint2* __restrict__ Hs2,
                                           const int* __restrict__ rp,
                                           const unsigned short* __restrict__ col,
                                           const float* __restrict__ dinv,
                                           float* __restrict__ Y,
                                           float* __restrict__ part, int n) {
    __shared__ float sS[4][64];
    __shared__ float sQ[4][64];
    int t = threadIdx.x;
    int w = t >> 6;
    int lane = t & 63;
    int q = lane >> 4;
    int c = lane & 15;
    int d = blockIdx.x * 4 + w;
    bool valid = d < n;
    int dc = valid ? d : 0;
    float ax = 0.f, ay = 0.f, az = 0.f, aw = 0.f;
    int beg = valid ? rp[dc] : 0;
    int end = valid ? rp[dc + 1] : 0;
    for (int b = beg; b < end; b += 64) {
        int m = min(64, end - b);
        int myidx = (lane < m) ? (int)col[b + lane] : 0;
        int jj = 0;
        for (; jj + 7 < m; jj += 8) {
            int s0 = __shfl(myidx, jj + q, 64);
            int s1 = __shfl(myidx, jj + 4 + q, 64);
            uint2 v0 = Hs2[(size_t)s0 * 16 + c];
            uint2 v1 = Hs2[(size_t)s1 * 16 + c];
            bf16x2_add(v0.x, ax, ay); bf16x2_add(v0.y, az, aw);
            bf16x2_add(v1.x, ax, ay); bf16x2_add(v1.y, az, aw);
        }
        for (; jj < m; jj += 4) {
            int e = jj + q;
            int s0 = __shfl(myidx, min(e, m - 1), 64);
            if (e < m) {
                uint2 v = Hs2[(size_t)s0 * 16 + c];
                bf16x2_add(v.x, ax, ay); bf16x2_add(v.y, az, aw);
            }
        }
    }
    ax += __shfl_xor(ax, 16, 64); ay += __shfl_xor(ay, 16, 64);
    az += __shfl_xor(az, 16, 64); aw += __shfl_xor(aw, 16, 64);
    ax += __shfl_xor(ax, 32, 64); ay += __shfl_xor(ay, 32, 64);
    az += __shfl_xor(az, 32, 64); aw += __shfl_xor(aw, 32, 64);
    if (q == 0) {
        float4 y = make_float4(0.f, 0.f, 0.f, 0.f);
        if (valid) {
            float hx = 0.f, hy = 0.f, hz = 0.f, hw = 0.f;
            uint2 hv = Hs2[(size_t)dc * 16 + c];
            bf16x2_add(hv.x, hx, hy); bf16x2_add(hv.y, hz, hw);
            float dv = dinv[dc];
            y.x = (ax + hx) * dv; y.y = (ay + hy) * dv;
            y.z = (az + hz) * dv; y.w = (aw + hw) * dv;
            *(float4*)&Y[(size_t)dc * 64 + c * 4] = y;
        }
        *(float4*)&sS[w][c * 4] = y;
        float4 yq = make_float4(y.x * y.x, y.y * y.y, y.z * y.z, y.w * y.w);
        *(float4*)&sQ[w][c * 4] = yq;
    }
    __syncthreads();
    if (t < 64) {
        float s = sS[0][t] + sS[1][t] + sS[2][t] + sS[3][t];
        float qq = sQ[0][t] + sQ[1][t] + sQ[2][t] + sQ[3][t];
        float* dst = part + (size_t)(blockIdx.x & (NSLICE - 1)) * 128;
        atomicAdd(&dst[t], s);
        atomicAdd(&dst[64 + t], qq);
    }
}

// layer-3 variant: no Y materialization; per-graph raw-y sums via atomics.
__global__ __launch_bounds__(256) void agg_pool(const uint2* __restrict__ Hs2,
                                                const int* __restrict__ rp,
                                                const unsigned short* __restrict__ col,
                                                const float* __restrict__ dinv,
                                                const int* __restrict__ batch,
                                                float* __restrict__ out,
                                                float* __restrict__ part, int n) {
    __shared__ float sS[4][64];
    __shared__ float sQ[4][64];
    __shared__ int sG[4];
    int t = threadIdx.x;
    int w = t >> 6;
    int lane = t & 63;
    int q = lane >> 4;
    int c = lane & 15;
    int d = blockIdx.x * 4 + w;
    bool valid = d < n;
    int dc = valid ? d : 0;
    float ax = 0.f, ay = 0.f, az = 0.f, aw = 0.f;
    int beg = valid ? rp[dc] : 0;
    int end = valid ? rp[dc + 1] : 0;
    for (int b = beg; b < end; b += 64) {
        int m = min(64, end - b);
        int myidx = (lane < m) ? (int)col[b + lane] : 0;
        int jj = 0;
        for (; jj + 7 < m; jj += 8) {
            int s0 = __shfl(myidx, jj + q, 64);
            int s1 = __shfl(myidx, jj + 4 + q, 64);
            uint2 v0 = Hs2[(size_t)s0 * 16 + c];
            uint2 v1 = Hs2[(size_t)s1 * 16 + c];
            bf16x2_add(v0.x, ax, ay); bf16x2_add(v0.y, az, aw);
            bf16x2_add(v1.x, ax, ay); bf16x2_add(v1.y, az, aw);
        }
        for (; jj < m; jj += 4) {
            int e = jj + q;
            int s0 = __shfl(myidx, min(e, m - 1), 64);
            if (e < m) {
                uint2 v = Hs2[(size_t)s0 * 16 + c];
                bf16x2_add(v.x, ax, ay); bf16x2_add(v.y, az, aw);
            }
        }
    }
    ax += __shfl_xor(ax, 16, 64); ay += __shfl_xor(ay, 16, 64);
    az += __shfl_xor(az, 16, 64); aw += __shfl_xor(aw, 16, 64);
    ax += __shfl_xor(ax, 32, 64); ay += __shfl_xor(ay, 32, 64);
    az += __shfl_xor(az, 32, 64); aw += __shfl_xor(aw, 32, 64);
    if (q == 0) {
        float4 y = make_float4(0.f, 0.f, 0.f, 0.f);
        if (valid) {
            float hx = 0.f, hy = 0.f, hz = 0.f, hw = 0.f;
            uint2 hv = Hs2[(size_t)dc * 16 + c];
            bf16x2_add(hv.x, hx, hy); bf16x2_add(hv.y, hz, hw);
            float dv = dinv[dc];
            y.x = (ax + hx) * dv; y.y = (ay + hy) * dv;
            y.z = (az + hz) * dv; y.w = (aw + hw) * dv;
        }
        *(float4*)&sS[w][c * 4] = y;
        float4 yq = make_float4(y.x * y.x, y.y * y.y, y.z * y.z, y.w * y.w);
        *(float4*)&sQ[w][c * 4] = yq;
        if (lane == 0) sG[w] = valid ? batch[dc] : -1;
    }
    __syncthreads();
    if (t < 64) {
        float s = sS[0][t] + sS[1][t] + sS[2][t] + sS[3][t];
        float qq = sQ[0][t] + sQ[1][t] + sQ[2][t] + sQ[3][t];
        float* dst = part + (size_t)(blockIdx.x & (NSLICE - 1)) * 128;
        atomicAdd(&dst[t], s);
        atomicAdd(&dst[64 + t], qq);
        int g0 = sG[0], g1 = sG[1], g2 = sG[2], g3 = sG[3];
        if (g0 >= 0 && g0 == g1 && g0 == g2 && g0 == g3) {
            atomicAdd(&out[(size_t)g0 * 64 + t], s);
        } else {
            if (g0 >= 0) atomicAdd(&out[(size_t)g0 * 64 + t], sS[0][t]);
            if (g1 >= 0) atomicAdd(&out[(size_t)g1 * 64 + t], sS[1][t]);
            if (g2 >= 0) atomicAdd(&out[(size_t)g2 * 64 + t], sS[2][t]);
            if (g3 >= 0) atomicAdd(&out[(size_t)g3 * 64 + t], sS[3][t]);
        }
    }
}

// ================= final: out = BN3-affine(graph mean), BN3 coeffs in-block =================

__global__ __launch_bounds__(256) void pool_div(float* __restrict__ out,
                                                const float* __restrict__ cnt,
                                                const float* __restrict__ part,
                                                const float* __restrict__ gamma,
                                                const float* __restrict__ beta,
                                                int G, float inv_n) {
    __shared__ float s_scsh[128];
    int t = threadIdx.x;
    if (t < 128) {
        float s = 0.f;
#pragma unroll
        for (int k = 0; k < NSLICE; ++k) s += part[k * 128 + t];
        s_scsh[t] = s;
    }
    __syncthreads();
    if (t < 64) {
        float mean = s_scsh[t] * inv_n;
        float var = s_scsh[64 + t] * inv_n - mean * mean;
        float sc = gamma[t] * rsqrtf(var + BN_EPS);
        s_scsh[t] = sc;
        s_scsh[64 + t] = beta[t] - mean * sc;
    }
    __syncthreads();
    int idx = blockIdx.x * 256 + t;
    if (idx >= G * 64) return;
    int j = idx & 63, g = idx >> 6;
    float c = cnt[g];
    out[idx] = (c > 0.5f) ? fmaf(s_scsh[j], out[idx] / c, s_scsh[64 + j]) : 0.f;
}

// ================= launch =================

extern "C" void kernel_launch(void* const* d_in, const int* in_sizes, int n_in,
                              void* d_out, int out_size, void* d_ws, size_t ws_size,
                              hipStream_t stream) {
    const float* x     = (const float*)d_in[0];
    const int*   ei    = (const int*)d_in[1];
    const int*   batch = (const int*)d_in[2];
    const float* Wl[3] = {(const float*)d_in[3], (const float*)d_in[7], (const float*)d_in[11]};
    const float* gl[3] = {(const float*)d_in[5], (const float*)d_in[9], (const float*)d_in[13]};
    const float* bl[3] = {(const float*)d_in[6], (const float*)d_in[10], (const float*)d_in[14]};
    float* out = (float*)d_out;

    int E = in_sizes[1] / 2;
    int n = in_sizes[0] / 64;
    int G = out_size / 64;
    const int* src = ei;
    const int* dst = ei + E;
    int NBC = (n + 255) / 256;  // coarse buckets (<=256 for n<=65536)
    float inv_n = 1.0f / (float)n;

    char* ws = (char*)d_ws;
    size_t off = 0;
    auto carve = [&](size_t bytes) {
        void* p = ws + off;
        off += (bytes + 255) & ~(size_t)255;
        return p;
    };
    // part + ccnt carved adjacently -> single memset covers both
    float*          part  = (float*)carve(3 * NSLICE * 128 * 4);  // 49152 B
    int*            ccnt  = (int*)carve(256 * 4);                  // 1024 B
    float*          dinv  = (float*)carve((size_t)n * 4);
    float*          cnt_g = (float*)carve((size_t)G * 4);
    unsigned*       Hs    = (unsigned*)carve((size_t)n * 32 * 4);  // n*64 bf16
    float*          Ybuf  = (float*)carve((size_t)n * 64 * 4);
    int*            cboff = (int*)carve(257 * 4);
    int*            gcur  = (int*)carve(256 * 4);
    int*            rp    = (int*)carve(((size_t)n + 1) * 4);
    unsigned*       tmp   = (unsigned*)carve((size_t)E * 4);
    unsigned short* col   = (unsigned short*)carve((size_t)E * 2);

    int pgrid = (E + CCH - 1) / CCH;

    // ---- setup: one memset (part+ccnt), CSR build + dinv + counts + zeroing ----
    hipMemsetAsync(part, 0, 3 * NSLICE * 128 * 4 + 256 * 4, stream);
    coarse_count<<<pgrid, 256, 0, stream>>>(dst, ccnt, E);
    cscan<<<1, 256, 0, stream>>>(ccnt, cboff, gcur, rp, cnt_g, out, NBC, n, E, G);
    cscatter<<<pgrid, 256, 0, stream>>>(src, dst, gcur, tmp, E);
    build_csr<<<NBC, 256, 0, stream>>>(tmp, cboff, rp, col, dinv, batch, cnt_g, n, G);

    int gemm_grid = (n + 63) / 64;
    int agg_grid = (n + 3) / 4;

    // ---- 3 GCN layers ----
    const float* cur = x;
    for (int l = 0; l < 3; ++l) {
        float* part_l = part + (size_t)l * NSLICE * 128;
        const float* part_prev = (l > 0) ? part + (size_t)(l - 1) * NSLICE * 128 : part;
        gemm64_v2<<<gemm_grid, 256, 0, stream>>>(cur, Wl[l], dinv, part_prev,
                                                 l > 0 ? gl[l - 1] : gl[0],
                                                 l > 0 ? bl[l - 1] : bl[0],
                                                 l > 0 ? 1 : 0, inv_n, Hs, n);
        if (l < 2) {
            agg<<<agg_grid, 256, 0, stream>>>((const uint2*)Hs, rp, col, dinv,
                                              Ybuf, part_l, n);
        } else {
            agg_pool<<<agg_grid, 256, 0, stream>>>((const uint2*)Hs, rp, col, dinv,
                                                   batch, out, part_l, n);
        }
        cur = Ybuf;
    }

    // ---- final BN3-affine on graph means (BN3 coeffs computed in-block) ----
    pool_div<<<(G * 64 + 255) / 256, 256, 0, stream>>>(out, cnt_g,
                                                       part + 2 * NSLICE * 128,
                                                       gl[2], bl[2], G, inv_n);
}